// Round 6
// baseline (302.113 us; speedup 1.0000x reference)
//
#include <hip/hip_runtime.h>
#include <hip/hip_bf16.h>
#include <stdint.h>
#include <stddef.h>

// SelfAttention: B=4 T=2048 E=1024 H=16 S=64, causal, q/k LayerNorm over S.
// f32 in/out; bf16 MFMA compute.
//   0) cvt_all: Wq/Wk/Wv/Wu and x f32 -> bf16 (one pass).
//   1) gemm_qkv: Q/K/V = x@W^T, fused head-LayerNorm (q,k), SCALE*log2(e)
//      folded in Q.  XCD remap + 2-phase dbuf staging, counted vmcnt. [r3]
//   2) flash: causal attention, STATIC softmax (LN bound; log2e folded into
//      Q so P = exp2(s) directly, no M0 — p and l co-scale by 2^12, ratio
//      exact; no running max; l-sum deferred to epilogue).
//      ROUND 6 (r5 regressed: 64-row blocks doubled per-row overhead; r4's
//      REAL occupancy cap was grid=512 = 2 blocks/CU total):
//      (a) grid (16,64)=1024 one-qt blocks, 512 thr, heavy-first (qt
//          descending within XCD) -> 3 blocks/CU resident possible;
//      (b) VT double-buffered, V(t+1) transposed right after the TOP
//          barrier -> PV reads VT[cur] written a tile ago -> the mid
//          lgkm+barrier is GONE: ONE barrier per tile (PT is wave-private,
//          own lgkmcnt(0) suffices);
//      (c) softmax = bare exp2f (C folded into Q, M0 dropped).
//      K tile: LDS dbuf via global_load_lds + both-sides XOR swizzle [r2];
//      counted waits, cvtpk P->bf16, mask-split, setprio [r4].
//   3) gemm_bias: out = attn@Wu^T + bu (same structure as gemm_qkv).
// Workspace: Q(=AO),K,V (48MB) + W bf16 (8MB) + xb (16MB) = 72MB (fallback
// template if ws_size < 72MB keeps the old f32-A staging, 1-phase loop).

using bf16 = __hip_bfloat16;
typedef __attribute__((ext_vector_type(8))) short s16x8;
typedef __attribute__((ext_vector_type(4))) short s16x4;
typedef __attribute__((ext_vector_type(4))) float f32x4;

#define MFMA16(a, b, c) __builtin_amdgcn_mfma_f32_16x16x32_bf16((a), (b), (c), 0, 0, 0)

static __device__ __forceinline__ s16x8 ld8(const bf16* p) {
    return *reinterpret_cast<const s16x8*>(p);
}
static __device__ __forceinline__ s16x8 ld8s(const short* p) {
    return *reinterpret_cast<const s16x8*>(p);
}
static __device__ __forceinline__ s16x8 cvt8(const float* p) {
    f32x4 u = *reinterpret_cast<const f32x4*>(p);
    f32x4 v = *reinterpret_cast<const f32x4*>(p + 4);
    s16x8 r;
#pragma unroll
    for (int e = 0; e < 4; e++) {
        r[e]     = __builtin_bit_cast(short, __float2bfloat16(u[e]));
        r[e + 4] = __builtin_bit_cast(short, __float2bfloat16(v[e]));
    }
    return r;
}
// packed f32x2 -> bf16x2 (RNE), 1 instr; no builtin on gfx950 (T12 recipe)
static __device__ __forceinline__ unsigned int cvtpk(float lo, float hi) {
    unsigned int r;
    asm("v_cvt_pk_bf16_f32 %0, %1, %2" : "=v"(r) : "v"(lo), "v"(hi));
    return r;
}

// async global(bf16)->LDS, 16B per lane; lds base must be wave-uniform.
static __device__ __forceinline__ void async16(short* lds, const bf16* g) {
    __builtin_amdgcn_global_load_lds(
        (const __attribute__((address_space(1))) unsigned int*)g,
        (__attribute__((address_space(3))) unsigned int*)lds, 16, 0, 0);
}

#define EE 1024

// ---------------------------------------------------------------------------
// f32 -> bf16: z=0..3 weights (1M each), z=4..11 x slices (8 x 1M)
// ---------------------------------------------------------------------------
__global__ __launch_bounds__(256) void cvt_all(
    const float* __restrict__ w0, const float* __restrict__ w1,
    const float* __restrict__ w2, const float* __restrict__ w3,
    const float* __restrict__ x,
    bf16* __restrict__ o0, bf16* __restrict__ o1,
    bf16* __restrict__ o2, bf16* __restrict__ o3, bf16* __restrict__ xb)
{
    const int z = blockIdx.z;
    const float* s;
    bf16* d;
    if (z < 4) {
        s = (z == 0) ? w0 : (z == 1) ? w1 : (z == 2) ? w2 : w3;
        d = (z == 0) ? o0 : (z == 1) ? o1 : (z == 2) ? o2 : o3;
    } else {
        s = x  + (size_t)(z - 4) * 1048576;
        d = xb + (size_t)(z - 4) * 1048576;
    }
    size_t i = ((size_t)blockIdx.x * 256 + threadIdx.x) * 8;
    *reinterpret_cast<s16x8*>(d + i) = cvt8(s + i);
}

// ---------------------------------------------------------------------------
// Fused QKV GEMM + head LayerNorm.  z=0:Q(+LN,*0.125*log2e) z=1:K(+LN) z=2:V
// AF32=0: 2-phase dbuf staging via global_load_lds from xb + XCD remap.
// AF32=1: f32 cvt fallback (old 1-phase structure).
// ---------------------------------------------------------------------------
template <int AF32>
__global__ __launch_bounds__(256) void gemm_qkv_t(
    const float* __restrict__ xf, const bf16* __restrict__ xb,
    const bf16* __restrict__ Wq, const bf16* __restrict__ Wk, const bf16* __restrict__ Wv,
    bf16* __restrict__ Qb, bf16* __restrict__ Kb, bf16* __restrict__ Vb,
    const float* __restrict__ qg, const float* __restrict__ qbt,
    const float* __restrict__ kg, const float* __restrict__ kbt)
{
    const int z = blockIdx.z;
    const bf16* Bt = (z == 0) ? Wq : (z == 1) ? Wk : Wv;
    bf16* out      = (z == 0) ? Qb : (z == 1) ? Kb : Vb;
    const float* gamma = (z == 0) ? qg : kg;
    const float* beta  = (z == 0) ? qbt : kbt;
    const bool  ln     = (z < 2);
    // log2(e) folded into Q so flash softmax is a bare exp2
    const float oscale = (z == 0) ? 0.125f * 1.44269504088896340736f : 1.0f;

    constexpr int LASZ = AF32 ? 128 * 40 : 2 * 4096;
    __shared__ __align__(16) short lA[LASZ];
    __shared__ __align__(16) short lB[2 * 4096];

    const int tid  = threadIdx.x;
    const int lane = tid & 63;
    const int w    = tid >> 6;
    const int wr = w >> 1, wc = w & 1;
    const int lr = lane & 15, quad = lane >> 4;

    // XCD-aware remap: XCD = flat%8 = blockIdx.x owns 8 contiguous m-panels
    const int mi = blockIdx.x * 8 + (blockIdx.y & 7);
    const int ni = blockIdx.y >> 3;
    const int m0 = mi * 128;
    const int n0 = ni * 128;

    const int strow = w * 32 + (lane >> 2);
    const int stcol = (lane & 3) * 8;
    const bf16* bgl = Bt + (size_t)(n0 + strow) * EE + stcol;

    f32x4 acc[4][4];
#pragma unroll
    for (int i = 0; i < 4; i++)
#pragma unroll
        for (int j = 0; j < 4; j++) acc[i][j] = (f32x4){0.f, 0.f, 0.f, 0.f};

    if constexpr (AF32) {
        constexpr int SA = 40;
        const int sr  = tid >> 1;
        const int sc0 = (tid & 1) << 4;
        const float* ap = xf + (size_t)(m0 + sr) * EE + sc0;
        short* lap = lA + sr * SA + sc0;
        short* bl = lB + (w * 2) * 512;
        const short* lArd = lA + (wr * 64 + lr) * SA + quad * 8;
        const short* lBrd = lB + (wc * 64 + lr) * 32 + quad * 8;
        const bf16* bg = bgl;

        for (int kt = 0; kt < EE / 32; ++kt) {
            s16x8 a0 = cvt8(ap), a1 = cvt8(ap + 8);
            __syncthreads();
            *reinterpret_cast<s16x8*>(lap)     = a0;
            *reinterpret_cast<s16x8*>(lap + 8) = a1;
            async16(bl, bg);
            async16(bl + 512, bg + 16 * EE);
            ap += 32;
            bg += 32;
            __syncthreads();

            s16x8 af[4], bfr[4];
#pragma unroll
            for (int i = 0; i < 4; i++) af[i]  = ld8s(lArd + i * 16 * SA);
#pragma unroll
            for (int j = 0; j < 4; j++) bfr[j] = ld8s(lBrd + j * 16 * 32);
#pragma unroll
            for (int i = 0; i < 4; i++)
#pragma unroll
                for (int j = 0; j < 4; j++) acc[i][j] = MFMA16(af[i], bfr[j], acc[i][j]);
        }
    } else {
        const bf16* agl = xb + (size_t)(m0 + strow) * EE + stcol;
        short* const al0 = lA + w * 1024;
        short* const bl0 = lB + w * 1024;

#define QSTAGE(c, kt)                                                     \
    {                                                                     \
        short* al = al0 + (c) * 4096;                                     \
        short* bl = bl0 + (c) * 4096;                                     \
        const bf16* ag = agl + (kt) * 32;                                 \
        const bf16* bg = bgl + (kt) * 32;                                 \
        async16(al, ag); async16(al + 512, ag + 16 * EE);                 \
        async16(bl, bg); async16(bl + 512, bg + 16 * EE);                 \
    }

        QSTAGE(0, 0)
#pragma unroll 1
        for (int kt = 0; kt < EE / 32; ++kt) {
            const int c = kt & 1;
            if (kt < EE / 32 - 1) {
                QSTAGE(c ^ 1, kt + 1)
                asm volatile("s_waitcnt vmcnt(4)" ::: "memory");
            } else {
                asm volatile("s_waitcnt vmcnt(0)" ::: "memory");
            }
            __builtin_amdgcn_s_barrier();   // stage(kt) landed for all waves

            const short* lArd = lA + c * 4096 + (wr * 64 + lr) * 32 + quad * 8;
            const short* lBrd = lB + c * 4096 + (wc * 64 + lr) * 32 + quad * 8;
            s16x8 af[4], bfr[4];
#pragma unroll
            for (int i = 0; i < 4; i++) af[i]  = ld8s(lArd + i * 512);
#pragma unroll
            for (int j = 0; j < 4; j++) bfr[j] = ld8s(lBrd + j * 512);
            __builtin_amdgcn_sched_barrier(0);
            asm volatile("s_waitcnt lgkmcnt(0)" ::: "memory");
            __builtin_amdgcn_sched_barrier(0);   // rule #18: pin MFMA below
#pragma unroll
            for (int i = 0; i < 4; i++)
#pragma unroll
                for (int j = 0; j < 4; j++) acc[i][j] = MFMA16(af[i], bfr[j], acc[i][j]);
            __builtin_amdgcn_s_barrier();   // reads of buf c done -> reusable
        }
#undef QSTAGE
    }

    if (ln) {
        float g[4], bt[4];
#pragma unroll
        for (int j = 0; j < 4; j++) {
            g[j]  = gamma[j * 16 + lr];
            bt[j] = beta[j * 16 + lr];
        }
#pragma unroll
        for (int i = 0; i < 4; i++) {
#pragma unroll
            for (int r = 0; r < 4; r++) {
                float s1 = 0.f, s2 = 0.f;
#pragma unroll
                for (int j = 0; j < 4; j++) {
                    float v = acc[i][j][r];
                    s1 += v;
                    s2 += v * v;
                }
#pragma unroll
                for (int off = 1; off < 16; off <<= 1) {
                    s1 += __shfl_xor(s1, off);
                    s2 += __shfl_xor(s2, off);
                }
                float mu  = s1 * (1.f / 64.f);
                float var = s2 * (1.f / 64.f) - mu * mu;
                float rs  = rsqrtf(var + 1e-5f);
                int row = m0 + wr * 64 + i * 16 + quad * 4 + r;
#pragma unroll
                for (int j = 0; j < 4; j++) {
                    float v = ((acc[i][j][r] - mu) * rs * g[j] + bt[j]) * oscale;
                    out[(size_t)row * EE + n0 + wc * 64 + j * 16 + lr] = __float2bfloat16(v);
                }
            }
        }
    } else {
#pragma unroll
        for (int i = 0; i < 4; i++)
#pragma unroll
            for (int r = 0; r < 4; r++) {
                int row = m0 + wr * 64 + i * 16 + quad * 4 + r;
#pragma unroll
                for (int j = 0; j < 4; j++)
                    out[(size_t)row * EE + n0 + wc * 64 + j * 16 + lr] =
                        __float2bfloat16(acc[i][j][r]);
            }
    }
}

// ---------------------------------------------------------------------------
// Causal flash attention.  grid (16,64) = 1024 blocks, 512 thr = 8 waves x
// 16 q-rows; one 128-row q-tile (qt) per block, heavy-first order.
// ONE barrier per tile: VT double-buffered (V(t+1) transposed right after
// the top barrier; PV reads VT[cur] written a tile ago).  K tile: LDS dbuf
// via global_load_lds + both-sides XOR swizzle.  PT wave-private (own
// lgkmcnt only).  Softmax = bare exp2f (log2e folded in Q, no M0).
// ---------------------------------------------------------------------------
__global__ __launch_bounds__(512, 4) void flash(
    const bf16* __restrict__ Qb, const bf16* __restrict__ Kb,
    const bf16* __restrict__ Vb, bf16* __restrict__ Ob)
{
    const int flat = blockIdx.y * 16 + blockIdx.x;
    const int vid  = (flat & 7) * 128 + (flat >> 3);  // bijective XCD swizzle
    const int bh = vid >> 4;                          // 8 bh per XCD
    const int qt = 15 - (vid & 15);                   // heavy blocks first
    const int b = bh >> 4, h = bh & 15;
    const int tid = threadIdx.x, lane = tid & 63, w = tid >> 6;   // w = 0..7
    const int lr = lane & 15, quad = lane >> 4;
    const size_t base = (size_t)b * 2048 * 1024 + h * 64;

    __shared__ __align__(16) short VT[2][64 * 72];  // V^T tiles [s][key], dbuf
    __shared__ __align__(16) short PT[128 * 72];    // P tile (wave-private rows)
    __shared__ __align__(16) short KS[2][64 * 64];  // K tiles, swizzled linear

    short* const prow = PT + (w * 16 + lr) * 72;    // wave-local P row
    const bf16* const kst = Kb + base + (size_t)(w * 8 + (lane >> 3)) * 1024 +
                            (((lane & 7) ^ (lane >> 3)) << 3);
    short* const kdst = &KS[0][0] + w * 512;
    const int kaddr0 = lr * 64 + ((quad ^ (lr & 7)) << 3);

    const int tw = qt * 128 + w * 16;
    const int nkt = 2 * qt + 2;   // even, >= 2

    // Q fragments (B operand: col=query=lr, k=quad*8), resident all tiles
    s16x8 qf[2];
#pragma unroll
    for (int ks = 0; ks < 2; ks++)
        qf[ks] = ld8(Qb + base + (size_t)(tw + lr) * 1024 + ks * 32 + quad * 8);

    f32x4 o[4];
#pragma unroll
    for (int j = 0; j < 4; j++) o[j] = (f32x4){0.f, 0.f, 0.f, 0.f};
    float lsum = 0.f;

    // prologue: K(0)->KS[0]; V(0) regs -> VT[0]; V(1) -> vb (in flight)
    async16(kdst, kst);
    s16x8 va = ld8(Vb + base + (size_t)lane * 1024 + w * 8);
    s16x8 vb = ld8(Vb + base + (size_t)(64 + lane) * 1024 + w * 8);
    asm volatile("s_waitcnt vmcnt(1)" ::: "memory");   // K(0)+va landed; vb in flight
#pragma unroll
    for (int e = 0; e < 8; e++)
        VT[0][(w * 8 + e) * 72 + lane] = va[e];

// FTILE(t): VWR holds V(t+1) (written to VT[cur^1]); VLD receives V(t+2).
#define FTILE(KT, VWR, KCUR, VLD)                                                \
    {                                                                            \
        const int kb = (KT) * 64;                                                \
        const bool active = (kb <= tw + 15);                                     \
        asm volatile("s_waitcnt vmcnt(0) lgkmcnt(0)" ::: "memory");              \
        __builtin_amdgcn_s_barrier();  /* K(t),V(t+1) landed; all reads done */  \
        _Pragma("unroll")                                                        \
        for (int e = 0; e < 8; e++)    /* V(t+1) -> VT[cur^1] */                 \
            VT[(KCUR) ^ 1][(w * 8 + e) * 72 + lane] = VWR[e];                    \
        const int kb2 = kb + 64, kb3 = kb + 128;                                 \
        if (kb2 < nkt * 64)            /* K(t+1); in flight across compute */    \
            async16(kdst + ((KCUR) ^ 1) * 4096, kst + (size_t)kb2 * 1024);       \
        if (kb3 < nkt * 64)            /* V(t+2) regs */                         \
            VLD = ld8(Vb + base + (size_t)(kb3 + lane) * 1024 + w * 8);          \
        if (active) {                                                            \
            const short* kc = &KS[KCUR][0];                                      \
            f32x4 sc[4];                                                         \
            _Pragma("unroll")                                                    \
            for (int jk = 0; jk < 4; jk++) sc[jk] = (f32x4){0.f, 0.f, 0.f, 0.f}; \
            __builtin_amdgcn_s_setprio(1);                                       \
            _Pragma("unroll")                                                    \
            for (int ks = 0; ks < 2; ks++)                                       \
                _Pragma("unroll")                                                \
                for (int jk = 0; jk < 4; jk++) {                                 \
                    s16x8 kf = ld8s(kc + jk * 1024 + (kaddr0 ^ (ks * 32)));      \
                    sc[jk] = MFMA16(kf, qf[ks], sc[jk]);                         \
                }                                                                \
            __builtin_amdgcn_s_setprio(0);                                       \
            if (kb + 63 > tw) {          /* diagonal tile: causal mask */        \
                const int qq = tw + lr;                                          \
                _Pragma("unroll")                                                \
                for (int jk = 0; jk < 4; jk++) {                                 \
                    const int k0 = kb + jk * 16 + quad * 4;                      \
                    float p0 = exp2f(sc[jk][0]);                                 \
                    float p1 = exp2f(sc[jk][1]);                                 \
                    float p2 = exp2f(sc[jk][2]);                                 \
                    float p3 = exp2f(sc[jk][3]);                                 \
                    if (k0 + 0 > qq) p0 = 0.f;                                   \
                    if (k0 + 1 > qq) p1 = 0.f;                                   \
                    if (k0 + 2 > qq) p2 = 0.f;                                   \
                    if (k0 + 3 > qq) p3 = 0.f;                                   \
                    lsum += (p0 + p1) + (p2 + p3);                               \
                    uint2 pk = {cvtpk(p0, p1), cvtpk(p2, p3)};                   \
                    *reinterpret_cast<uint2*>(prow + jk * 16 + quad * 4) = pk;   \
                }                                                                \
            } else {                     /* interior tile: no mask */            \
                _Pragma("unroll")                                                \
                for (int jk = 0; jk < 4; jk++) {                                 \
                    float p0 = exp2f(sc[jk][0]);                                 \
                    float p1 = exp2f(sc[jk][1]);                                 \
                    float p2 = exp2f(sc[jk][2]);                                 \
                    float p3 = exp2f(sc[jk][3]);                                 \
                    lsum += (p0 + p1) + (p2 + p3);                               \
                    uint2 pk = {cvtpk(p0, p1), cvtpk(p2, p3)};                   \
                    *reinterpret_cast<uint2*>(prow + jk * 16 + quad * 4) = pk;   \
                }                                                                \
            }                                                                    \
            asm volatile("s_waitcnt lgkmcnt(0)" ::: "memory"); /* own PT done */ \
            __builtin_amdgcn_sched_barrier(0);                                   \
            _Pragma("unroll")                                                    \
            for (int ks = 0; ks < 2; ks++) {                                     \
                s16x8 pf = ld8s(prow + ks * 32 + quad * 8);                      \
                s16x8 vf[4];                                                     \
                _Pragma("unroll")                                                \
                for (int j = 0; j < 4; j++)                                      \
                    vf[j] = ld8s(&VT[KCUR][0] + (j * 16 + lr) * 72 +             \
                                 ks * 32 + quad * 8);                            \
                __builtin_amdgcn_s_setprio(1);                                   \
                _Pragma("unroll")                                                \
                for (int j = 0; j < 4; j++)                                      \
                    o[j] = MFMA16(pf, vf[j], o[j]);                              \
                __builtin_amdgcn_s_setprio(0);                                   \
            }                                                                    \
        }                                                                        \
    }

    int kt = 0;
#pragma unroll 1
    for (; kt + 2 <= nkt; kt += 2) {
        FTILE(kt,     vb, 0, va)
        FTILE(kt + 1, va, 1, vb)
    }
#undef FTILE

    // epilogue: finish l reduction (deferred), normalize, store
    float l = lsum;
    l += __shfl_xor(l, 16);
    l += __shfl_xor(l, 32);
#pragma unroll
    for (int r = 0; r < 4; r++) {
        float inv = 1.f / __shfl(l, quad * 4 + r);
        int t = tw + quad * 4 + r;
#pragma unroll
        for (int j = 0; j < 4; j++)
            Ob[base + (size_t)t * 1024 + j * 16 + lr] =
                __float2bfloat16(o[j][r] * inv);
    }
}

// ---------------------------------------------------------------------------
// out = A @ Wu^T + bu  (2-phase dbuf staging + XCD remap, as gemm_qkv)
// ---------------------------------------------------------------------------
__global__ __launch_bounds__(256) void gemm_bias(
    const bf16* __restrict__ A, const bf16* __restrict__ Bt,
    const float* __restrict__ bias, float* __restrict__ out)
{
    __shared__ __align__(16) short lA[2 * 4096];
    __shared__ __align__(16) short lB[2 * 4096];

    const int tid  = threadIdx.x;
    const int lane = tid & 63;
    const int w    = tid >> 6;
    const int wr = w >> 1, wc = w & 1;
    const int lr = lane & 15, quad = lane >> 4;

    const int mi = blockIdx.x * 8 + (blockIdx.y & 7);
    const int ni = blockIdx.y >> 3;
    const int m0 = mi * 128;
    const int n0 = ni * 128;

    const int strow = w * 32 + (lane >> 2);
    const int stcol = (lane & 3) * 8;
    const bf16* agl = A  + (size_t)(m0 + strow) * EE + stcol;
    const bf16* bgl = Bt + (size_t)(n0 + strow) * EE + stcol;
    short* const al0 = lA + w * 1024;
    short* const bl0 = lB + w * 1024;

    f32x4 acc[4][4];
#pragma unroll
    for (int i = 0; i < 4; i++)
#pragma unroll
        for (int j = 0; j < 4; j++) acc[i][j] = (f32x4){0.f, 0.f, 0.f, 0.f};

#define BSTAGE(c, kt)                                                     \
    {                                                                     \
        short* al = al0 + (c) * 4096;                                     \
        short* bl = bl0 + (c) * 4096;                                     \
        const bf16* ag = agl + (kt) * 32;                                 \
        const bf16* bg = bgl + (kt) * 32;                                 \
        async16(al, ag); async16(al + 512, ag + 16 * EE);                 \
        async16(bl, bg); async16(bl + 512, bg + 16 * EE);                 \
    }

    BSTAGE(0, 0)
#pragma unroll 1
    for (int kt = 0; kt < EE / 32; ++kt) {
        const int c = kt & 1;
        if (kt < EE / 32 - 1) {
            BSTAGE(c ^ 1, kt + 1)
            asm volatile("s_waitcnt vmcnt(4)" ::: "memory");
        } else {
            asm volatile("s_waitcnt vmcnt(0)" ::: "memory");
        }
        __builtin_amdgcn_s_barrier();

        const short* lArd = lA + c * 4096 + (wr * 64 + lr) * 32 + quad * 8;
        const short* lBrd = lB + c * 4096 + (wc * 64 + lr) * 32 + quad * 8;
        s16x8 af[4], bfr[4];
#pragma unroll
        for (int i = 0; i < 4; i++) af[i]  = ld8s(lArd + i * 512);
#pragma unroll
        for (int j = 0; j < 4; j++) bfr[j] = ld8s(lBrd + j * 512);
        __builtin_amdgcn_sched_barrier(0);
        asm volatile("s_waitcnt lgkmcnt(0)" ::: "memory");
        __builtin_amdgcn_sched_barrier(0);
#pragma unroll
        for (int i = 0; i < 4; i++)
#pragma unroll
            for (int j = 0; j < 4; j++) acc[i][j] = MFMA16(af[i], bfr[j], acc[i][j]);
        __builtin_amdgcn_s_barrier();
    }
#undef BSTAGE

    float bz[4];
#pragma unroll
    for (int j = 0; j < 4; j++)
        bz[j] = bias[n0 + wc * 64 + j * 16 + lr];
#pragma unroll
    for (int i = 0; i < 4; i++)
#pragma unroll
        for (int r = 0; r < 4; r++) {
            int row = m0 + wr * 64 + i * 16 + quad * 4 + r;
#pragma unroll
            for (int j = 0; j < 4; j++)
                out[(size_t)row * EE + n0 + wc * 64 + j * 16 + lr] =
                    acc[i][j][r] + bz[j];
        }
}

// ---------------------------------------------------------------------------
extern "C" void kernel_launch(void* const* d_in, const int* in_sizes, int n_in,
                              void* d_out, int out_size, void* d_ws, size_t ws_size,
                              hipStream_t stream)
{
    (void)in_sizes; (void)n_in; (void)out_size;
    const float* x   = (const float*)d_in[0];
    const float* Wq  = (const float*)d_in[1];
    const float* Wk  = (const float*)d_in[2];
    const float* Wv  = (const float*)d_in[3];
    const float* Wu  = (const float*)d_in[4];
    const float* bu  = (const float*)d_in[5];
    const float* qg  = (const float*)d_in[6];
    const float* qbt = (const float*)d_in[7];
    const float* kg  = (const float*)d_in[8];
    const float* kbt = (const float*)d_in[9];
    float* out = (float*)d_out;

    bf16* Qb  = (bf16*)d_ws;                    // 16MB (doubles as attn-out)
    bf16* Kb  = Qb  + (size_t)8192 * 1024;
    bf16* Vb  = Kb  + (size_t)8192 * 1024;
    bf16* Wqb = Vb  + (size_t)8192 * 1024;      // 2MB each
    bf16* Wkb = Wqb + (size_t)1024 * 1024;
    bf16* Wvb = Wkb + (size_t)1024 * 1024;
    bf16* Wub = Wvb + (size_t)1024 * 1024;
    bf16* xb  = Wub + (size_t)1024 * 1024;      // 16MB

    const size_t need = ((size_t)3 * 8192 * 1024 + 4 * 1024 * 1024 + 8192 * 1024) * 2;
    const bool fast = ws_size >= need;

    cvt_all<<<dim3(512, 1, fast ? 12 : 4), 256, 0, stream>>>(
        Wq, Wk, Wv, Wu, x, Wqb, Wkb, Wvb, Wub, xb);
    if (fast)
        gemm_qkv_t<0><<<dim3(8, 64, 3), 256, 0, stream>>>(
            x, xb, Wqb, Wkb, Wvb, Qb, Kb, Vb, qg, qbt, kg, kbt);
    else
        gemm_qkv_t<1><<<dim3(8, 64, 3), 256, 0, stream>>>(
            x, nullptr, Wqb, Wkb, Wvb, Qb, Kb, Vb, qg, qbt, kg, kbt);
    flash<<<dim3(16, 64), 512, 0, stream>>>(Qb, Kb, Vb, Qb);
    gemm_bias<<<dim3(8, 64), 256, 0, stream>>>(Qb, Wub, bu, out);
}

// Round 7
// 271.214 us; speedup vs baseline: 1.1139x; 1.1139x over previous
//
#include <hip/hip_runtime.h>
#include <hip/hip_bf16.h>
#include <stdint.h>
#include <stddef.h>

// SelfAttention: B=4 T=2048 E=1024 H=16 S=64, causal, q/k LayerNorm over S.
// f32 in/out; bf16 MFMA compute.
//   0) cvt_all: Wq/Wk/Wv/Wu and x f32 -> bf16 (one pass).
//   1) gemm_qkv: Q/K/V = x@W^T, fused head-LayerNorm (q,k), SCALE*log2(e)
//      folded in Q.  XCD remap + 2-phase dbuf staging, counted vmcnt [r3].
//      ROUND 7: LDS fragment reads were 4-way bank-conflicted (stride 16
//      dwords) -> both-sides XOR chunk swizzle (source (lane&3)^(strow&3),
//      read quad^(lr&3)) -> 2-way (free).
//   2) flash: REVERTED to the r4 partition (r5/r6 lesson: the (p,15-p)
//      pairing = equal 36-tile blocks is what makes 2-blocks/CU pack
//      perfectly; variable-length blocks stretch the makespan).  grid
//      (8,64), 512 thr, 2 barriers/tile, K-LDS dbuf + V reg prefetch.
//      ROUND 7: VT/PT were 8-way bank-conflicted (stride-72 rows: phase
//      slots 4(lr+quad)mod32) = the constant 7.57M SQ_LDS_BANK_CONFLICT
//      since r2 -> XOR-swizzled 64-wide layouts (chunk ^= row&7, write and
//      read sides) -> conflict-free PV.  LDS 44->40KB.  Softmax stays bare
//      exp2f (log2e folded in Q epilogue, verified r6).
//   3) gemm_bias: out = attn@Wu^T + bu (same structure + XOR as gemm_qkv).
// Workspace: Q(=AO),K,V (48MB) + W bf16 (8MB) + xb (16MB) = 72MB (fallback
// template if ws_size < 72MB keeps the old f32-A staging, 1-phase loop).

using bf16 = __hip_bfloat16;
typedef __attribute__((ext_vector_type(8))) short s16x8;
typedef __attribute__((ext_vector_type(4))) short s16x4;
typedef __attribute__((ext_vector_type(4))) float f32x4;

#define MFMA16(a, b, c) __builtin_amdgcn_mfma_f32_16x16x32_bf16((a), (b), (c), 0, 0, 0)

static __device__ __forceinline__ s16x8 ld8(const bf16* p) {
    return *reinterpret_cast<const s16x8*>(p);
}
static __device__ __forceinline__ s16x8 ld8s(const short* p) {
    return *reinterpret_cast<const s16x8*>(p);
}
static __device__ __forceinline__ s16x8 cvt8(const float* p) {
    f32x4 u = *reinterpret_cast<const f32x4*>(p);
    f32x4 v = *reinterpret_cast<const f32x4*>(p + 4);
    s16x8 r;
#pragma unroll
    for (int e = 0; e < 4; e++) {
        r[e]     = __builtin_bit_cast(short, __float2bfloat16(u[e]));
        r[e + 4] = __builtin_bit_cast(short, __float2bfloat16(v[e]));
    }
    return r;
}
// packed f32x2 -> bf16x2 (RNE), 1 instr; no builtin on gfx950 (T12 recipe)
static __device__ __forceinline__ unsigned int cvtpk(float lo, float hi) {
    unsigned int r;
    asm("v_cvt_pk_bf16_f32 %0, %1, %2" : "=v"(r) : "v"(lo), "v"(hi));
    return r;
}

// async global(bf16)->LDS, 16B per lane; lds base must be wave-uniform.
static __device__ __forceinline__ void async16(short* lds, const bf16* g) {
    __builtin_amdgcn_global_load_lds(
        (const __attribute__((address_space(1))) unsigned int*)g,
        (__attribute__((address_space(3))) unsigned int*)lds, 16, 0, 0);
}

#define EE 1024

// ---------------------------------------------------------------------------
// f32 -> bf16: z=0..3 weights (1M each), z=4..11 x slices (8 x 1M)
// ---------------------------------------------------------------------------
__global__ __launch_bounds__(256) void cvt_all(
    const float* __restrict__ w0, const float* __restrict__ w1,
    const float* __restrict__ w2, const float* __restrict__ w3,
    const float* __restrict__ x,
    bf16* __restrict__ o0, bf16* __restrict__ o1,
    bf16* __restrict__ o2, bf16* __restrict__ o3, bf16* __restrict__ xb)
{
    const int z = blockIdx.z;
    const float* s;
    bf16* d;
    if (z < 4) {
        s = (z == 0) ? w0 : (z == 1) ? w1 : (z == 2) ? w2 : w3;
        d = (z == 0) ? o0 : (z == 1) ? o1 : (z == 2) ? o2 : o3;
    } else {
        s = x  + (size_t)(z - 4) * 1048576;
        d = xb + (size_t)(z - 4) * 1048576;
    }
    size_t i = ((size_t)blockIdx.x * 256 + threadIdx.x) * 8;
    *reinterpret_cast<s16x8*>(d + i) = cvt8(s + i);
}

// ---------------------------------------------------------------------------
// Fused QKV GEMM + head LayerNorm.  z=0:Q(+LN,*0.125*log2e) z=1:K(+LN) z=2:V
// AF32=0: 2-phase dbuf staging via global_load_lds from xb + XCD remap +
//         both-sides XOR chunk swizzle on lA/lB.
// AF32=1: f32 cvt fallback (old 1-phase structure, linear LDS).
// ---------------------------------------------------------------------------
template <int AF32>
__global__ __launch_bounds__(256) void gemm_qkv_t(
    const float* __restrict__ xf, const bf16* __restrict__ xb,
    const bf16* __restrict__ Wq, const bf16* __restrict__ Wk, const bf16* __restrict__ Wv,
    bf16* __restrict__ Qb, bf16* __restrict__ Kb, bf16* __restrict__ Vb,
    const float* __restrict__ qg, const float* __restrict__ qbt,
    const float* __restrict__ kg, const float* __restrict__ kbt)
{
    const int z = blockIdx.z;
    const bf16* Bt = (z == 0) ? Wq : (z == 1) ? Wk : Wv;
    bf16* out      = (z == 0) ? Qb : (z == 1) ? Kb : Vb;
    const float* gamma = (z == 0) ? qg : kg;
    const float* beta  = (z == 0) ? qbt : kbt;
    const bool  ln     = (z < 2);
    // log2(e) folded into Q so flash softmax is a bare exp2
    const float oscale = (z == 0) ? 0.125f * 1.44269504088896340736f : 1.0f;

    constexpr int LASZ = AF32 ? 128 * 40 : 2 * 4096;
    __shared__ __align__(16) short lA[LASZ];
    __shared__ __align__(16) short lB[2 * 4096];

    const int tid  = threadIdx.x;
    const int lane = tid & 63;
    const int w    = tid >> 6;
    const int wr = w >> 1, wc = w & 1;
    const int lr = lane & 15, quad = lane >> 4;

    // XCD-aware remap: XCD = flat%8 = blockIdx.x owns 8 contiguous m-panels
    const int mi = blockIdx.x * 8 + (blockIdx.y & 7);
    const int ni = blockIdx.y >> 3;
    const int m0 = mi * 128;
    const int n0 = ni * 128;

    const int strow = w * 32 + (lane >> 2);
    // both-sides XOR: source chunk = (lane&3)^(strow&3); read chunk = quad^(row&3)
    const int stcol = AF32 ? (lane & 3) * 8
                           : (((lane & 3) ^ (strow & 3)) << 3);
    const bf16* bgl = Bt + (size_t)(n0 + strow) * EE + stcol;

    f32x4 acc[4][4];
#pragma unroll
    for (int i = 0; i < 4; i++)
#pragma unroll
        for (int j = 0; j < 4; j++) acc[i][j] = (f32x4){0.f, 0.f, 0.f, 0.f};

    if constexpr (AF32) {
        constexpr int SA = 40;
        const int sr  = tid >> 1;
        const int sc0 = (tid & 1) << 4;
        const float* ap = xf + (size_t)(m0 + sr) * EE + sc0;
        short* lap = lA + sr * SA + sc0;
        short* bl = lB + (w * 2) * 512;
        const short* lArd = lA + (wr * 64 + lr) * SA + quad * 8;
        const short* lBrd = lB + (wc * 64 + lr) * 32 + quad * 8;
        const bf16* bg = bgl;

        for (int kt = 0; kt < EE / 32; ++kt) {
            s16x8 a0 = cvt8(ap), a1 = cvt8(ap + 8);
            __syncthreads();
            *reinterpret_cast<s16x8*>(lap)     = a0;
            *reinterpret_cast<s16x8*>(lap + 8) = a1;
            async16(bl, bg);
            async16(bl + 512, bg + 16 * EE);
            ap += 32;
            bg += 32;
            __syncthreads();

            s16x8 af[4], bfr[4];
#pragma unroll
            for (int i = 0; i < 4; i++) af[i]  = ld8s(lArd + i * 16 * SA);
#pragma unroll
            for (int j = 0; j < 4; j++) bfr[j] = ld8s(lBrd + j * 16 * 32);
#pragma unroll
            for (int i = 0; i < 4; i++)
#pragma unroll
                for (int j = 0; j < 4; j++) acc[i][j] = MFMA16(af[i], bfr[j], acc[i][j]);
        }
    } else {
        const bf16* agl = xb + (size_t)(m0 + strow) * EE + stcol;
        short* const al0 = lA + w * 1024;
        short* const bl0 = lB + w * 1024;

#define QSTAGE(c, kt)                                                     \
    {                                                                     \
        short* al = al0 + (c) * 4096;                                     \
        short* bl = bl0 + (c) * 4096;                                     \
        const bf16* ag = agl + (kt) * 32;                                 \
        const bf16* bg = bgl + (kt) * 32;                                 \
        async16(al, ag); async16(al + 512, ag + 16 * EE);                 \
        async16(bl, bg); async16(bl + 512, bg + 16 * EE);                 \
    }

        QSTAGE(0, 0)
        // read chunk = quad ^ (row&3); row = w?*64 + lr -> row&3 = lr&3
        const int ard = (wr * 64 + lr) * 32 + ((quad ^ (lr & 3)) << 3);
        const int brd = (wc * 64 + lr) * 32 + ((quad ^ (lr & 3)) << 3);
#pragma unroll 1
        for (int kt = 0; kt < EE / 32; ++kt) {
            const int c = kt & 1;
            if (kt < EE / 32 - 1) {
                QSTAGE(c ^ 1, kt + 1)
                asm volatile("s_waitcnt vmcnt(4)" ::: "memory");
            } else {
                asm volatile("s_waitcnt vmcnt(0)" ::: "memory");
            }
            __builtin_amdgcn_s_barrier();   // stage(kt) landed for all waves

            const short* lArd = lA + c * 4096 + ard;
            const short* lBrd = lB + c * 4096 + brd;
            s16x8 af[4], bfr[4];
#pragma unroll
            for (int i = 0; i < 4; i++) af[i]  = ld8s(lArd + i * 512);
#pragma unroll
            for (int j = 0; j < 4; j++) bfr[j] = ld8s(lBrd + j * 512);
            __builtin_amdgcn_sched_barrier(0);
            asm volatile("s_waitcnt lgkmcnt(0)" ::: "memory");
            __builtin_amdgcn_sched_barrier(0);   // rule #18: pin MFMA below
#pragma unroll
            for (int i = 0; i < 4; i++)
#pragma unroll
                for (int j = 0; j < 4; j++) acc[i][j] = MFMA16(af[i], bfr[j], acc[i][j]);
            __builtin_amdgcn_s_barrier();   // reads of buf c done -> reusable
        }
#undef QSTAGE
    }

    if (ln) {
        float g[4], bt[4];
#pragma unroll
        for (int j = 0; j < 4; j++) {
            g[j]  = gamma[j * 16 + lr];
            bt[j] = beta[j * 16 + lr];
        }
#pragma unroll
        for (int i = 0; i < 4; i++) {
#pragma unroll
            for (int r = 0; r < 4; r++) {
                float s1 = 0.f, s2 = 0.f;
#pragma unroll
                for (int j = 0; j < 4; j++) {
                    float v = acc[i][j][r];
                    s1 += v;
                    s2 += v * v;
                }
#pragma unroll
                for (int off = 1; off < 16; off <<= 1) {
                    s1 += __shfl_xor(s1, off);
                    s2 += __shfl_xor(s2, off);
                }
                float mu  = s1 * (1.f / 64.f);
                float var = s2 * (1.f / 64.f) - mu * mu;
                float rs  = rsqrtf(var + 1e-5f);
                int row = m0 + wr * 64 + i * 16 + quad * 4 + r;
#pragma unroll
                for (int j = 0; j < 4; j++) {
                    float v = ((acc[i][j][r] - mu) * rs * g[j] + bt[j]) * oscale;
                    out[(size_t)row * EE + n0 + wc * 64 + j * 16 + lr] = __float2bfloat16(v);
                }
            }
        }
    } else {
#pragma unroll
        for (int i = 0; i < 4; i++)
#pragma unroll
            for (int r = 0; r < 4; r++) {
                int row = m0 + wr * 64 + i * 16 + quad * 4 + r;
#pragma unroll
                for (int j = 0; j < 4; j++)
                    out[(size_t)row * EE + n0 + wc * 64 + j * 16 + lr] =
                        __float2bfloat16(acc[i][j][r]);
            }
    }
}

// ---------------------------------------------------------------------------
// Causal flash attention.  grid (8,64), 512 thr = 8 waves x 16 q-rows,
// balanced pairs (pr, 15-pr) = equal 36-tile blocks, 2 blocks/CU.
// K tile: LDS dbuf via global_load_lds + both-sides XOR swizzle.
// VT/PT: XOR-swizzled 64-wide (chunk ^= row&7 on write AND read) ->
// conflict-free PV ds ops.  V: reg prefetch + LDS transpose.  Counted
// waits; bare exp2f softmax; cvtpk; mask-split; setprio.
// ---------------------------------------------------------------------------
__global__ __launch_bounds__(512, 4) void flash(
    const bf16* __restrict__ Qb, const bf16* __restrict__ Kb,
    const bf16* __restrict__ Vb, bf16* __restrict__ Ob)
{
    const int flat = blockIdx.y * 8 + blockIdx.x;
    const int vid  = (flat & 7) * 64 + (flat >> 3);   // bijective XCD swizzle
    const int pr = vid & 7;
    const int bh = vid >> 3;
    const int b = bh >> 4, h = bh & 15;
    const int tid = threadIdx.x, lane = tid & 63, w = tid >> 6;   // w = 0..7
    const int lr = lane & 15, quad = lane >> 4;
    const size_t base = (size_t)b * 2048 * 1024 + h * 64;

    __shared__ __align__(16) short VT[64 * 64];     // V^T tile, XOR-swizzled
    __shared__ __align__(16) short PT[128 * 64];    // P tile, XOR-swizzled
    __shared__ __align__(16) short KS[2][64 * 64];  // K tiles, swizzled linear

    short* const prow = PT + (w * 16 + lr) * 64;    // wave-local P row base
    const int lr7 = lr & 7;
    const bf16* const kst = Kb + base + (size_t)(w * 8 + (lane >> 3)) * 1024 +
                            (((lane & 7) ^ (lane >> 3)) << 3);
    short* const kdst = &KS[0][0] + w * 512;
    const int kaddr0 = lr * 64 + ((quad ^ lr7) << 3);

#pragma unroll 1
    for (int ph = 0; ph < 2; ++ph) {
        const int qt = ph ? (15 - pr) : pr;
        const int tw = qt * 128 + w * 16;

        // Q fragments (B operand: col=query=lr, k=quad*8), resident all tiles
        s16x8 qf[2];
#pragma unroll
        for (int ks = 0; ks < 2; ks++)
            qf[ks] = ld8(Qb + base + (size_t)(tw + lr) * 1024 + ks * 32 + quad * 8);

        f32x4 o[4];
#pragma unroll
        for (int j = 0; j < 4; j++) o[j] = (f32x4){0.f, 0.f, 0.f, 0.f};
        float lsum = 0.f;

        const int nkt = 2 * qt + 2;   // even

        __syncthreads();   // KS/VT/PT reuse across phases (prev reads done)
        // prefetch tile 0: V to regs, K to KS[0]
        s16x8 va0 = ld8(Vb + base + (size_t)lane * 1024 + w * 8);
        s16x8 vb0;
        async16(kdst, kst);

#define FTILE(KT, V0C, KCUR, V0N, KNXT)                                          \
    {                                                                            \
        const int kb = (KT) * 64;                                                \
        const bool active = (kb <= tw + 15);                                     \
        asm volatile("s_waitcnt vmcnt(0)" ::: "memory"); /* K/V(t) landed */     \
        __builtin_amdgcn_s_barrier();  /* + prior iter's VT/PT reads done */     \
        _Pragma("unroll")                                                        \
        for (int e = 0; e < 8; e++)    /* V^T write, swizzled: row=w*8+e */      \
            VT[(w * 8 + e) * 64 + (((lane >> 3) ^ e) << 3) + (lane & 7)]         \
                = V0C[e];                                                        \
        const int kb2 = kb + 64;                                                 \
        if (kb2 < nkt * 64) { /* prefetch t+1; stays in flight across PV */      \
            async16(kdst + (KNXT) * 4096, kst + (size_t)kb2 * 1024);             \
            V0N = ld8(Vb + base + (size_t)(kb2 + lane) * 1024 + w * 8);          \
        }                                                                        \
        if (active) {                                                            \
            const short* kc = &KS[KCUR][0];                                      \
            f32x4 sc[4];                                                         \
            _Pragma("unroll")                                                    \
            for (int jk = 0; jk < 4; jk++) sc[jk] = (f32x4){0.f, 0.f, 0.f, 0.f}; \
            __builtin_amdgcn_s_setprio(1);                                       \
            _Pragma("unroll")                                                    \
            for (int ks = 0; ks < 2; ks++)                                       \
                _Pragma("unroll")                                                \
                for (int jk = 0; jk < 4; jk++) {                                 \
                    s16x8 kf = ld8s(kc + jk * 1024 + (kaddr0 ^ (ks * 32)));      \
                    sc[jk] = MFMA16(kf, qf[ks], sc[jk]);                         \
                }                                                                \
            __builtin_amdgcn_s_setprio(0);                                       \
            if (kb + 63 > tw) {          /* diagonal tile: causal mask */        \
                const int qq = tw + lr;                                          \
                _Pragma("unroll")                                                \
                for (int jk = 0; jk < 4; jk++) {                                 \
                    const int k0 = kb + jk * 16 + quad * 4;                      \
                    float p0 = exp2f(sc[jk][0]);                                 \
                    float p1 = exp2f(sc[jk][1]);                                 \
                    float p2 = exp2f(sc[jk][2]);                                 \
                    float p3 = exp2f(sc[jk][3]);                                 \
                    if (k0 + 0 > qq) p0 = 0.f;                                   \
                    if (k0 + 1 > qq) p1 = 0.f;                                   \
                    if (k0 + 2 > qq) p2 = 0.f;                                   \
                    if (k0 + 3 > qq) p3 = 0.f;                                   \
                    lsum += (p0 + p1) + (p2 + p3);                               \
                    uint2 pk = {cvtpk(p0, p1), cvtpk(p2, p3)};                   \
                    *reinterpret_cast<uint2*>(                                   \
                        prow + (((jk * 2 + (quad >> 1)) ^ lr7) << 3) +           \
                        ((quad & 1) << 2)) = pk;                                 \
                }                                                                \
            } else {                     /* interior tile: no mask */            \
                _Pragma("unroll")                                                \
                for (int jk = 0; jk < 4; jk++) {                                 \
                    float p0 = exp2f(sc[jk][0]);                                 \
                    float p1 = exp2f(sc[jk][1]);                                 \
                    float p2 = exp2f(sc[jk][2]);                                 \
                    float p3 = exp2f(sc[jk][3]);                                 \
                    lsum += (p0 + p1) + (p2 + p3);                               \
                    uint2 pk = {cvtpk(p0, p1), cvtpk(p2, p3)};                   \
                    *reinterpret_cast<uint2*>(                                   \
                        prow + (((jk * 2 + (quad >> 1)) ^ lr7) << 3) +           \
                        ((quad & 1) << 2)) = pk;                                 \
                }                                                                \
            }                                                                    \
        }                                                                        \
        asm volatile("s_waitcnt lgkmcnt(0)" ::: "memory"); /* VT/PT visible */   \
        __builtin_amdgcn_s_barrier();  /* prefetch NOT drained */                \
        if (active) {                                                            \
            _Pragma("unroll")                                                    \
            for (int ks = 0; ks < 2; ks++) {                                     \
                s16x8 pf = ld8s(prow + (((ks * 4 + quad) ^ lr7) << 3));          \
                s16x8 vf[4];                                                     \
                _Pragma("unroll")                                                \
                for (int j = 0; j < 4; j++)                                      \
                    vf[j] = ld8s(VT + (j * 16 + lr) * 64 +                       \
                                 (((ks * 4 + quad) ^ lr7) << 3));                \
                __builtin_amdgcn_s_setprio(1);                                   \
                _Pragma("unroll")                                                \
                for (int j = 0; j < 4; j++)                                      \
                    o[j] = MFMA16(pf, vf[j], o[j]);                              \
                __builtin_amdgcn_s_setprio(0);                                   \
            }                                                                    \
        }                                                                        \
    }

#pragma unroll 1
        for (int kt = 0; kt < nkt; kt += 2) {
            FTILE(kt,     va0, 0, vb0, 1)
            FTILE(kt + 1, vb0, 1, va0, 0)
        }
#undef FTILE

        // epilogue: finish l reduction (deferred), normalize, store
        float l = lsum;
        l += __shfl_xor(l, 16);
        l += __shfl_xor(l, 32);
#pragma unroll
        for (int r = 0; r < 4; r++) {
            float inv = 1.f / __shfl(l, quad * 4 + r);
            int t = tw + quad * 4 + r;
#pragma unroll
            for (int j = 0; j < 4; j++)
                Ob[base + (size_t)t * 1024 + j * 16 + lr] =
                    __float2bfloat16(o[j][r] * inv);
        }
    }
}

// ---------------------------------------------------------------------------
// out = A @ Wu^T + bu  (2-phase dbuf staging + XCD remap + XOR chunk swizzle)
// ---------------------------------------------------------------------------
__global__ __launch_bounds__(256) void gemm_bias(
    const bf16* __restrict__ A, const bf16* __restrict__ Bt,
    const float* __restrict__ bias, float* __restrict__ out)
{
    __shared__ __align__(16) short lA[2 * 4096];
    __shared__ __align__(16) short lB[2 * 4096];

    const int tid  = threadIdx.x;
    const int lane = tid & 63;
    const int w    = tid >> 6;
    const int wr = w >> 1, wc = w & 1;
    const int lr = lane & 15, quad = lane >> 4;

    const int mi = blockIdx.x * 8 + (blockIdx.y & 7);
    const int ni = blockIdx.y >> 3;
    const int m0 = mi * 128;
    const int n0 = ni * 128;

    const int strow = w * 32 + (lane >> 2);
    const int stcol = (((lane & 3) ^ (strow & 3)) << 3);   // both-sides XOR
    const bf16* agl = A  + (size_t)(m0 + strow) * EE + stcol;
    const bf16* bgl = Bt + (size_t)(n0 + strow) * EE + stcol;
    short* const al0 = lA + w * 1024;
    short* const bl0 = lB + w * 1024;

    f32x4 acc[4][4];
#pragma unroll
    for (int i = 0; i < 4; i++)
#pragma unroll
        for (int j = 0; j < 4; j++) acc[i][j] = (f32x4){0.f, 0.f, 0.f, 0.f};

#define BSTAGE(c, kt)                                                     \
    {                                                                     \
        short* al = al0 + (c) * 4096;                                     \
        short* bl = bl0 + (c) * 4096;                                     \
        const bf16* ag = agl + (kt) * 32;                                 \
        const bf16* bg = bgl + (kt) * 32;                                 \
        async16(al, ag); async16(al + 512, ag + 16 * EE);                 \
        async16(bl, bg); async16(bl + 512, bg + 16 * EE);                 \
    }

    BSTAGE(0, 0)
    const int ard = (wr * 64 + lr) * 32 + ((quad ^ (lr & 3)) << 3);
    const int brd = (wc * 64 + lr) * 32 + ((quad ^ (lr & 3)) << 3);
#pragma unroll 1
    for (int kt = 0; kt < EE / 32; ++kt) {
        const int c = kt & 1;
        if (kt < EE / 32 - 1) {
            BSTAGE(c ^ 1, kt + 1)
            asm volatile("s_waitcnt vmcnt(4)" ::: "memory");
        } else {
            asm volatile("s_waitcnt vmcnt(0)" ::: "memory");
        }
        __builtin_amdgcn_s_barrier();

        const short* lArd = lA + c * 4096 + ard;
        const short* lBrd = lB + c * 4096 + brd;
        s16x8 af[4], bfr[4];
#pragma unroll
        for (int i = 0; i < 4; i++) af[i]  = ld8s(lArd + i * 512);
#pragma unroll
        for (int j = 0; j < 4; j++) bfr[j] = ld8s(lBrd + j * 512);
        __builtin_amdgcn_sched_barrier(0);
        asm volatile("s_waitcnt lgkmcnt(0)" ::: "memory");
        __builtin_amdgcn_sched_barrier(0);
#pragma unroll
        for (int i = 0; i < 4; i++)
#pragma unroll
            for (int j = 0; j < 4; j++) acc[i][j] = MFMA16(af[i], bfr[j], acc[i][j]);
        __builtin_amdgcn_s_barrier();
    }
#undef BSTAGE

    float bz[4];
#pragma unroll
    for (int j = 0; j < 4; j++)
        bz[j] = bias[n0 + wc * 64 + j * 16 + lr];
#pragma unroll
    for (int i = 0; i < 4; i++)
#pragma unroll
        for (int r = 0; r < 4; r++) {
            int row = m0 + wr * 64 + i * 16 + quad * 4 + r;
#pragma unroll
            for (int j = 0; j < 4; j++)
                out[(size_t)row * EE + n0 + wc * 64 + j * 16 + lr] =
                    acc[i][j][r] + bz[j];
        }
}

// ---------------------------------------------------------------------------
extern "C" void kernel_launch(void* const* d_in, const int* in_sizes, int n_in,
                              void* d_out, int out_size, void* d_ws, size_t ws_size,
                              hipStream_t stream)
{
    (void)in_sizes; (void)n_in; (void)out_size;
    const float* x   = (const float*)d_in[0];
    const float* Wq  = (const float*)d_in[1];
    const float* Wk  = (const float*)d_in[2];
    const float* Wv  = (const float*)d_in[3];
    const float* Wu  = (const float*)d_in[4];
    const float* bu  = (const float*)d_in[5];
    const float* qg  = (const float*)d_in[6];
    const float* qbt = (const float*)d_in[7];
    const float* kg  = (const float*)d_in[8];
    const float* kbt = (const float*)d_in[9];
    float* out = (float*)d_out;

    bf16* Qb  = (bf16*)d_ws;                    // 16MB (doubles as attn-out)
    bf16* Kb  = Qb  + (size_t)8192 * 1024;
    bf16* Vb  = Kb  + (size_t)8192 * 1024;
    bf16* Wqb = Vb  + (size_t)8192 * 1024;      // 2MB each
    bf16* Wkb = Wqb + (size_t)1024 * 1024;
    bf16* Wvb = Wkb + (size_t)1024 * 1024;
    bf16* Wub = Wvb + (size_t)1024 * 1024;
    bf16* xb  = Wub + (size_t)1024 * 1024;      // 16MB

    const size_t need = ((size_t)3 * 8192 * 1024 + 4 * 1024 * 1024 + 8192 * 1024) * 2;
    const bool fast = ws_size >= need;

    cvt_all<<<dim3(512, 1, fast ? 12 : 4), 256, 0, stream>>>(
        Wq, Wk, Wv, Wu, x, Wqb, Wkb, Wvb, Wub, xb);
    if (fast)
        gemm_qkv_t<0><<<dim3(8, 64, 3), 256, 0, stream>>>(
            x, xb, Wqb, Wkb, Wvb, Qb, Kb, Vb, qg, qbt, kg, kbt);
    else
        gemm_qkv_t<1><<<dim3(8, 64, 3), 256, 0, stream>>>(
            x, nullptr, Wqb, Wkb, Wvb, Qb, Kb, Vb, qg, qbt, kg, kbt);
    flash<<<dim3(8, 64), 512, 0, stream>>>(Qb, Kb, Vb, Qb);
    gemm_bias<<<dim3(8, 64), 256, 0, stream>>>(Qb, Wub, bu, out);
}

// Round 8
// 269.351 us; speedup vs baseline: 1.1216x; 1.0069x over previous
//
#include <hip/hip_runtime.h>
#include <hip/hip_bf16.h>
#include <stdint.h>
#include <stddef.h>

// SelfAttention: B=4 T=2048 E=1024 H=16 S=64, causal, q/k LayerNorm over S.
// f32 in/out; bf16 MFMA compute.
//   0) cvt_all: Wq/Wk/Wv/Wu and x f32 -> bf16 (one pass).
//   1) gemm_qkv: Q/K/V = x@W^T, fused head-LayerNorm (q,k), SCALE*log2(e)
//      folded in Q.  XCD remap + 2-phase dbuf staging, counted vmcnt [r3],
//      XOR chunk swizzle [r7].
//      ROUND 8: REMOVED the manual lgkmcnt(0)+sched_barrier(0) pins between
//      ds_reads and MFMAs (m141 lesson: order-pinning defeats the compiler's
//      fine-grained lgkmcnt(4/3/1/0) interleave; 605 TF measured = m141's
//      510-TF zone).  Rule #18 applies to inline-asm ds_reads only; these
//      are compiler loads with tracked deps.  Ordering: top vmcnt asm
//      ("memory") + s_barrier fence staging; compiler drains lgkm naturally
//      before the last MFMA, which precedes the bottom barrier.
//   2) flash: r7 structure unchanged (grid (8,64), 512 thr, balanced pairs,
//      K-LDS dbuf + both-sides XOR, VT/PT swizzled-64, counted waits, bare
//      exp2f softmax (log2e folded in Q), cvtpk, mask-split, setprio).
//   3) gemm_bias: out = attn@Wu^T + bu (same de-pinned structure).
// Workspace: Q(=AO),K,V (48MB) + W bf16 (8MB) + xb (16MB) = 72MB (fallback
// template if ws_size < 72MB keeps the old f32-A staging, 1-phase loop).

using bf16 = __hip_bfloat16;
typedef __attribute__((ext_vector_type(8))) short s16x8;
typedef __attribute__((ext_vector_type(4))) short s16x4;
typedef __attribute__((ext_vector_type(4))) float f32x4;

#define MFMA16(a, b, c) __builtin_amdgcn_mfma_f32_16x16x32_bf16((a), (b), (c), 0, 0, 0)

static __device__ __forceinline__ s16x8 ld8(const bf16* p) {
    return *reinterpret_cast<const s16x8*>(p);
}
static __device__ __forceinline__ s16x8 ld8s(const short* p) {
    return *reinterpret_cast<const s16x8*>(p);
}
static __device__ __forceinline__ s16x8 cvt8(const float* p) {
    f32x4 u = *reinterpret_cast<const f32x4*>(p);
    f32x4 v = *reinterpret_cast<const f32x4*>(p + 4);
    s16x8 r;
#pragma unroll
    for (int e = 0; e < 4; e++) {
        r[e]     = __builtin_bit_cast(short, __float2bfloat16(u[e]));
        r[e + 4] = __builtin_bit_cast(short, __float2bfloat16(v[e]));
    }
    return r;
}
// packed f32x2 -> bf16x2 (RNE), 1 instr; no builtin on gfx950 (T12 recipe)
static __device__ __forceinline__ unsigned int cvtpk(float lo, float hi) {
    unsigned int r;
    asm("v_cvt_pk_bf16_f32 %0, %1, %2" : "=v"(r) : "v"(lo), "v"(hi));
    return r;
}

// async global(bf16)->LDS, 16B per lane; lds base must be wave-uniform.
static __device__ __forceinline__ void async16(short* lds, const bf16* g) {
    __builtin_amdgcn_global_load_lds(
        (const __attribute__((address_space(1))) unsigned int*)g,
        (__attribute__((address_space(3))) unsigned int*)lds, 16, 0, 0);
}

#define EE 1024

// ---------------------------------------------------------------------------
// f32 -> bf16: z=0..3 weights (1M each), z=4..11 x slices (8 x 1M)
// ---------------------------------------------------------------------------
__global__ __launch_bounds__(256) void cvt_all(
    const float* __restrict__ w0, const float* __restrict__ w1,
    const float* __restrict__ w2, const float* __restrict__ w3,
    const float* __restrict__ x,
    bf16* __restrict__ o0, bf16* __restrict__ o1,
    bf16* __restrict__ o2, bf16* __restrict__ o3, bf16* __restrict__ xb)
{
    const int z = blockIdx.z;
    const float* s;
    bf16* d;
    if (z < 4) {
        s = (z == 0) ? w0 : (z == 1) ? w1 : (z == 2) ? w2 : w3;
        d = (z == 0) ? o0 : (z == 1) ? o1 : (z == 2) ? o2 : o3;
    } else {
        s = x  + (size_t)(z - 4) * 1048576;
        d = xb + (size_t)(z - 4) * 1048576;
    }
    size_t i = ((size_t)blockIdx.x * 256 + threadIdx.x) * 8;
    *reinterpret_cast<s16x8*>(d + i) = cvt8(s + i);
}

// ---------------------------------------------------------------------------
// Fused QKV GEMM + head LayerNorm.  z=0:Q(+LN,*0.125*log2e) z=1:K(+LN) z=2:V
// AF32=0: 2-phase dbuf staging via global_load_lds from xb + XCD remap +
//         both-sides XOR chunk swizzle on lA/lB; compiler-scheduled inner
//         loop (no manual lgkm pins).
// AF32=1: f32 cvt fallback (old 1-phase structure, linear LDS).
// ---------------------------------------------------------------------------
template <int AF32>
__global__ __launch_bounds__(256) void gemm_qkv_t(
    const float* __restrict__ xf, const bf16* __restrict__ xb,
    const bf16* __restrict__ Wq, const bf16* __restrict__ Wk, const bf16* __restrict__ Wv,
    bf16* __restrict__ Qb, bf16* __restrict__ Kb, bf16* __restrict__ Vb,
    const float* __restrict__ qg, const float* __restrict__ qbt,
    const float* __restrict__ kg, const float* __restrict__ kbt)
{
    const int z = blockIdx.z;
    const bf16* Bt = (z == 0) ? Wq : (z == 1) ? Wk : Wv;
    bf16* out      = (z == 0) ? Qb : (z == 1) ? Kb : Vb;
    const float* gamma = (z == 0) ? qg : kg;
    const float* beta  = (z == 0) ? qbt : kbt;
    const bool  ln     = (z < 2);
    // log2(e) folded into Q so flash softmax is a bare exp2
    const float oscale = (z == 0) ? 0.125f * 1.44269504088896340736f : 1.0f;

    constexpr int LASZ = AF32 ? 128 * 40 : 2 * 4096;
    __shared__ __align__(16) short lA[LASZ];
    __shared__ __align__(16) short lB[2 * 4096];

    const int tid  = threadIdx.x;
    const int lane = tid & 63;
    const int w    = tid >> 6;
    const int wr = w >> 1, wc = w & 1;
    const int lr = lane & 15, quad = lane >> 4;

    // XCD-aware remap: XCD = flat%8 = blockIdx.x owns 8 contiguous m-panels
    const int mi = blockIdx.x * 8 + (blockIdx.y & 7);
    const int ni = blockIdx.y >> 3;
    const int m0 = mi * 128;
    const int n0 = ni * 128;

    const int strow = w * 32 + (lane >> 2);
    // both-sides XOR: source chunk = (lane&3)^(strow&3); read chunk = quad^(lr&3)
    const int stcol = AF32 ? (lane & 3) * 8
                           : (((lane & 3) ^ (strow & 3)) << 3);
    const bf16* bgl = Bt + (size_t)(n0 + strow) * EE + stcol;

    f32x4 acc[4][4];
#pragma unroll
    for (int i = 0; i < 4; i++)
#pragma unroll
        for (int j = 0; j < 4; j++) acc[i][j] = (f32x4){0.f, 0.f, 0.f, 0.f};

    if constexpr (AF32) {
        constexpr int SA = 40;
        const int sr  = tid >> 1;
        const int sc0 = (tid & 1) << 4;
        const float* ap = xf + (size_t)(m0 + sr) * EE + sc0;
        short* lap = lA + sr * SA + sc0;
        short* bl = lB + (w * 2) * 512;
        const short* lArd = lA + (wr * 64 + lr) * SA + quad * 8;
        const short* lBrd = lB + (wc * 64 + lr) * 32 + quad * 8;
        const bf16* bg = bgl;

        for (int kt = 0; kt < EE / 32; ++kt) {
            s16x8 a0 = cvt8(ap), a1 = cvt8(ap + 8);
            __syncthreads();
            *reinterpret_cast<s16x8*>(lap)     = a0;
            *reinterpret_cast<s16x8*>(lap + 8) = a1;
            async16(bl, bg);
            async16(bl + 512, bg + 16 * EE);
            ap += 32;
            bg += 32;
            __syncthreads();

            s16x8 af[4], bfr[4];
#pragma unroll
            for (int i = 0; i < 4; i++) af[i]  = ld8s(lArd + i * 16 * SA);
#pragma unroll
            for (int j = 0; j < 4; j++) bfr[j] = ld8s(lBrd + j * 16 * 32);
#pragma unroll
            for (int i = 0; i < 4; i++)
#pragma unroll
                for (int j = 0; j < 4; j++) acc[i][j] = MFMA16(af[i], bfr[j], acc[i][j]);
        }
    } else {
        const bf16* agl = xb + (size_t)(m0 + strow) * EE + stcol;
        short* const al0 = lA + w * 1024;
        short* const bl0 = lB + w * 1024;

#define QSTAGE(c, kt)                                                     \
    {                                                                     \
        short* al = al0 + (c) * 4096;                                     \
        short* bl = bl0 + (c) * 4096;                                     \
        const bf16* ag = agl + (kt) * 32;                                 \
        const bf16* bg = bgl + (kt) * 32;                                 \
        async16(al, ag); async16(al + 512, ag + 16 * EE);                 \
        async16(bl, bg); async16(bl + 512, bg + 16 * EE);                 \
    }

        QSTAGE(0, 0)
        // read chunk = quad ^ (row&3); row = w?*64 + lr -> row&3 = lr&3
        const int ard = (wr * 64 + lr) * 32 + ((quad ^ (lr & 3)) << 3);
        const int brd = (wc * 64 + lr) * 32 + ((quad ^ (lr & 3)) << 3);
#pragma unroll 1
        for (int kt = 0; kt < EE / 32; ++kt) {
            const int c = kt & 1;
            if (kt < EE / 32 - 1) {
                QSTAGE(c ^ 1, kt + 1)
                asm volatile("s_waitcnt vmcnt(4)" ::: "memory");
            } else {
                asm volatile("s_waitcnt vmcnt(0)" ::: "memory");
            }
            __builtin_amdgcn_s_barrier();   // stage(kt) landed for all waves

            // compiler-scheduled: ds_reads interleave with MFMAs via
            // fine-grained lgkmcnt (no manual pins — m141 lesson)
            const short* lArd = lA + c * 4096 + ard;
            const short* lBrd = lB + c * 4096 + brd;
            s16x8 af[4], bfr[4];
#pragma unroll
            for (int i = 0; i < 4; i++) af[i]  = ld8s(lArd + i * 512);
#pragma unroll
            for (int j = 0; j < 4; j++) bfr[j] = ld8s(lBrd + j * 512);
#pragma unroll
            for (int i = 0; i < 4; i++)
#pragma unroll
                for (int j = 0; j < 4; j++) acc[i][j] = MFMA16(af[i], bfr[j], acc[i][j]);
            __builtin_amdgcn_s_barrier();   // reads of buf c done -> reusable
        }
#undef QSTAGE
    }

    if (ln) {
        float g[4], bt[4];
#pragma unroll
        for (int j = 0; j < 4; j++) {
            g[j]  = gamma[j * 16 + lr];
            bt[j] = beta[j * 16 + lr];
        }
#pragma unroll
        for (int i = 0; i < 4; i++) {
#pragma unroll
            for (int r = 0; r < 4; r++) {
                float s1 = 0.f, s2 = 0.f;
#pragma unroll
                for (int j = 0; j < 4; j++) {
                    float v = acc[i][j][r];
                    s1 += v;
                    s2 += v * v;
                }
#pragma unroll
                for (int off = 1; off < 16; off <<= 1) {
                    s1 += __shfl_xor(s1, off);
                    s2 += __shfl_xor(s2, off);
                }
                float mu  = s1 * (1.f / 64.f);
                float var = s2 * (1.f / 64.f) - mu * mu;
                float rs  = rsqrtf(var + 1e-5f);
                int row = m0 + wr * 64 + i * 16 + quad * 4 + r;
#pragma unroll
                for (int j = 0; j < 4; j++) {
                    float v = ((acc[i][j][r] - mu) * rs * g[j] + bt[j]) * oscale;
                    out[(size_t)row * EE + n0 + wc * 64 + j * 16 + lr] = __float2bfloat16(v);
                }
            }
        }
    } else {
#pragma unroll
        for (int i = 0; i < 4; i++)
#pragma unroll
            for (int r = 0; r < 4; r++) {
                int row = m0 + wr * 64 + i * 16 + quad * 4 + r;
#pragma unroll
                for (int j = 0; j < 4; j++)
                    out[(size_t)row * EE + n0 + wc * 64 + j * 16 + lr] =
                        __float2bfloat16(acc[i][j][r]);
            }
    }
}

// ---------------------------------------------------------------------------
// Causal flash attention.  grid (8,64), 512 thr = 8 waves x 16 q-rows,
// balanced pairs (pr, 15-pr) = equal 36-tile blocks, 2 blocks/CU.
// K tile: LDS dbuf via global_load_lds + both-sides XOR swizzle.
// VT/PT: XOR-swizzled 64-wide (chunk ^= row&7 on write AND read).
// V: reg prefetch + LDS transpose.  Counted waits; bare exp2f softmax;
// cvtpk; mask-split; setprio.  [unchanged from r7]
// ---------------------------------------------------------------------------
__global__ __launch_bounds__(512, 4) void flash(
    const bf16* __restrict__ Qb, const bf16* __restrict__ Kb,
    const bf16* __restrict__ Vb, bf16* __restrict__ Ob)
{
    const int flat = blockIdx.y * 8 + blockIdx.x;
    const int vid  = (flat & 7) * 64 + (flat >> 3);   // bijective XCD swizzle
    const int pr = vid & 7;
    const int bh = vid >> 3;
    const int b = bh >> 4, h = bh & 15;
    const int tid = threadIdx.x, lane = tid & 63, w = tid >> 6;   // w = 0..7
    const int lr = lane & 15, quad = lane >> 4;
    const size_t base = (size_t)b * 2048 * 1024 + h * 64;

    __shared__ __align__(16) short VT[64 * 64];     // V^T tile, XOR-swizzled
    __shared__ __align__(16) short PT[128 * 64];    // P tile, XOR-swizzled
    __shared__ __align__(16) short KS[2][64 * 64];  // K tiles, swizzled linear

    short* const prow = PT + (w * 16 + lr) * 64;    // wave-local P row base
    const int lr7 = lr & 7;
    const bf16* const kst = Kb + base + (size_t)(w * 8 + (lane >> 3)) * 1024 +
                            (((lane & 7) ^ (lane >> 3)) << 3);
    short* const kdst = &KS[0][0] + w * 512;
    const int kaddr0 = lr * 64 + ((quad ^ lr7) << 3);

#pragma unroll 1
    for (int ph = 0; ph < 2; ++ph) {
        const int qt = ph ? (15 - pr) : pr;
        const int tw = qt * 128 + w * 16;

        // Q fragments (B operand: col=query=lr, k=quad*8), resident all tiles
        s16x8 qf[2];
#pragma unroll
        for (int ks = 0; ks < 2; ks++)
            qf[ks] = ld8(Qb + base + (size_t)(tw + lr) * 1024 + ks * 32 + quad * 8);

        f32x4 o[4];
#pragma unroll
        for (int j = 0; j < 4; j++) o[j] = (f32x4){0.f, 0.f, 0.f, 0.f};
        float lsum = 0.f;

        const int nkt = 2 * qt + 2;   // even

        __syncthreads();   // KS/VT/PT reuse across phases (prev reads done)
        // prefetch tile 0: V to regs, K to KS[0]
        s16x8 va0 = ld8(Vb + base + (size_t)lane * 1024 + w * 8);
        s16x8 vb0;
        async16(kdst, kst);

#define FTILE(KT, V0C, KCUR, V0N, KNXT)                                          \
    {                                                                            \
        const int kb = (KT) * 64;                                                \
        const bool active = (kb <= tw + 15);                                     \
        asm volatile("s_waitcnt vmcnt(0)" ::: "memory"); /* K/V(t) landed */     \
        __builtin_amdgcn_s_barrier();  /* + prior iter's VT/PT reads done */     \
        _Pragma("unroll")                                                        \
        for (int e = 0; e < 8; e++)    /* V^T write, swizzled: row=w*8+e */      \
            VT[(w * 8 + e) * 64 + (((lane >> 3) ^ e) << 3) + (lane & 7)]         \
                = V0C[e];                                                        \
        const int kb2 = kb + 64;                                                 \
        if (kb2 < nkt * 64) { /* prefetch t+1; stays in flight across PV */      \
            async16(kdst + (KNXT) * 4096, kst + (size_t)kb2 * 1024);             \
            V0N = ld8(Vb + base + (size_t)(kb2 + lane) * 1024 + w * 8);          \
        }                                                                        \
        if (active) {                                                            \
            const short* kc = &KS[KCUR][0];                                      \
            f32x4 sc[4];                                                         \
            _Pragma("unroll")                                                    \
            for (int jk = 0; jk < 4; jk++) sc[jk] = (f32x4){0.f, 0.f, 0.f, 0.f}; \
            __builtin_amdgcn_s_setprio(1);                                       \
            _Pragma("unroll")                                                    \
            for (int ks = 0; ks < 2; ks++)                                       \
                _Pragma("unroll")                                                \
                for (int jk = 0; jk < 4; jk++) {                                 \
                    s16x8 kf = ld8s(kc + jk * 1024 + (kaddr0 ^ (ks * 32)));      \
                    sc[jk] = MFMA16(kf, qf[ks], sc[jk]);                         \
                }                                                                \
            __builtin_amdgcn_s_setprio(0);                                       \
            if (kb + 63 > tw) {          /* diagonal tile: causal mask */        \
                const int qq = tw + lr;                                          \
                _Pragma("unroll")                                                \
                for (int jk = 0; jk < 4; jk++) {                                 \
                    const int k0 = kb + jk * 16 + quad * 4;                      \
                    float p0 = exp2f(sc[jk][0]);                                 \
                    float p1 = exp2f(sc[jk][1]);                                 \
                    float p2 = exp2f(sc[jk][2]);                                 \
                    float p3 = exp2f(sc[jk][3]);                                 \
                    if (k0 + 0 > qq) p0 = 0.f;                                   \
                    if (k0 + 1 > qq) p1 = 0.f;                                   \
                    if (k0 + 2 > qq) p2 = 0.f;                                   \
                    if (k0 + 3 > qq) p3 = 0.f;                                   \
                    lsum += (p0 + p1) + (p2 + p3);                               \
                    uint2 pk = {cvtpk(p0, p1), cvtpk(p2, p3)};                   \
                    *reinterpret_cast<uint2*>(                                   \
                        prow + (((jk * 2 + (quad >> 1)) ^ lr7) << 3) +           \
                        ((quad & 1) << 2)) = pk;                                 \
                }                                                                \
            } else {                     /* interior tile: no mask */            \
                _Pragma("unroll")                                                \
                for (int jk = 0; jk < 4; jk++) {                                 \
                    float p0 = exp2f(sc[jk][0]);                                 \
                    float p1 = exp2f(sc[jk][1]);                                 \
                    float p2 = exp2f(sc[jk][2]);                                 \
                    float p3 = exp2f(sc[jk][3]);                                 \
                    lsum += (p0 + p1) + (p2 + p3);                               \
                    uint2 pk = {cvtpk(p0, p1), cvtpk(p2, p3)};                   \
                    *reinterpret_cast<uint2*>(                                   \
                        prow + (((jk * 2 + (quad >> 1)) ^ lr7) << 3) +           \
                        ((quad & 1) << 2)) = pk;                                 \
                }                                                                \
            }                                                                    \
        }                                                                        \
        asm volatile("s_waitcnt lgkmcnt(0)" ::: "memory"); /* VT/PT visible */   \
        __builtin_amdgcn_s_barrier();  /* prefetch NOT drained */                \
        if (active) {                                                            \
            _Pragma("unroll")                                                    \
            for (int ks = 0; ks < 2; ks++) {                                     \
                s16x8 pf = ld8s(prow + (((ks * 4 + quad) ^ lr7) << 3));          \
                s16x8 vf[4];                                                     \
                _Pragma("unroll")                                                \
                for (int j = 0; j < 4; j++)                                      \
                    vf[j] = ld8s(VT + (j * 16 + lr) * 64 +                       \
                                 (((ks * 4 + quad) ^ lr7) << 3));                \
                __builtin_amdgcn_s_setprio(1);                                   \
                _Pragma("unroll")                                                \
                for (int j = 0; j < 4; j++)                                      \
                    o[j] = MFMA16(pf, vf[j], o[j]);                              \
                __builtin_amdgcn_s_setprio(0);                                   \
            }                                                                    \
        }                                                                        \
    }

#pragma unroll 1
        for (int kt = 0; kt < nkt; kt += 2) {
            FTILE(kt,     va0, 0, vb0, 1)
            FTILE(kt + 1, vb0, 1, va0, 0)
        }
#undef FTILE

        // epilogue: finish l reduction (deferred), normalize, store
        float l = lsum;
        l += __shfl_xor(l, 16);
        l += __shfl_xor(l, 32);
#pragma unroll
        for (int r = 0; r < 4; r++) {
            float inv = 1.f / __shfl(l, quad * 4 + r);
            int t = tw + quad * 4 + r;
#pragma unroll
            for (int j = 0; j < 4; j++)
                Ob[base + (size_t)t * 1024 + j * 16 + lr] =
                    __float2bfloat16(o[j][r] * inv);
        }
    }
}

// ---------------------------------------------------------------------------
// out = A @ Wu^T + bu  (2-phase dbuf + XCD remap + XOR swizzle, de-pinned)
// ---------------------------------------------------------------------------
__global__ __launch_bounds__(256) void gemm_bias(
    const bf16* __restrict__ A, const bf16* __restrict__ Bt,
    const float* __restrict__ bias, float* __restrict__ out)
{
    __shared__ __align__(16) short lA[2 * 4096];
    __shared__ __align__(16) short lB[2 * 4096];

    const int tid  = threadIdx.x;
    const int lane = tid & 63;
    const int w    = tid >> 6;
    const int wr = w >> 1, wc = w & 1;
    const int lr = lane & 15, quad = lane >> 4;

    const int mi = blockIdx.x * 8 + (blockIdx.y & 7);
    const int ni = blockIdx.y >> 3;
    const int m0 = mi * 128;
    const int n0 = ni * 128;

    const int strow = w * 32 + (lane >> 2);
    const int stcol = (((lane & 3) ^ (strow & 3)) << 3);   // both-sides XOR
    const bf16* agl = A  + (size_t)(m0 + strow) * EE + stcol;
    const bf16* bgl = Bt + (size_t)(n0 + strow) * EE + stcol;
    short* const al0 = lA + w * 1024;
    short* const bl0 = lB + w * 1024;

    f32x4 acc[4][4];
#pragma unroll
    for (int i = 0; i < 4; i++)
#pragma unroll
        for (int j = 0; j < 4; j++) acc[i][j] = (f32x4){0.f, 0.f, 0.f, 0.f};

#define BSTAGE(c, kt)                                                     \
    {                                                                     \
        short* al = al0 + (c) * 4096;                                     \
        short* bl = bl0 + (c) * 4096;                                     \
        const bf16* ag = agl + (kt) * 32;                                 \
        const bf16* bg = bgl + (kt) * 32;                                 \
        async16(al, ag); async16(al + 512, ag + 16 * EE);                 \
        async16(bl, bg); async16(bl + 512, bg + 16 * EE);                 \
    }

    BSTAGE(0, 0)
    const int ard = (wr * 64 + lr) * 32 + ((quad ^ (lr & 3)) << 3);
    const int brd = (wc * 64 + lr) * 32 + ((quad ^ (lr & 3)) << 3);
#pragma unroll 1
    for (int kt = 0; kt < EE / 32; ++kt) {
        const int c = kt & 1;
        if (kt < EE / 32 - 1) {
            BSTAGE(c ^ 1, kt + 1)
            asm volatile("s_waitcnt vmcnt(4)" ::: "memory");
        } else {
            asm volatile("s_waitcnt vmcnt(0)" ::: "memory");
        }
        __builtin_amdgcn_s_barrier();

        // compiler-scheduled ds_read/MFMA interleave (no manual pins)
        const short* lArd = lA + c * 4096 + ard;
        const short* lBrd = lB + c * 4096 + brd;
        s16x8 af[4], bfr[4];
#pragma unroll
        for (int i = 0; i < 4; i++) af[i]  = ld8s(lArd + i * 512);
#pragma unroll
        for (int j = 0; j < 4; j++) bfr[j] = ld8s(lBrd + j * 512);
#pragma unroll
        for (int i = 0; i < 4; i++)
#pragma unroll
            for (int j = 0; j < 4; j++) acc[i][j] = MFMA16(af[i], bfr[j], acc[i][j]);
        __builtin_amdgcn_s_barrier();
    }
#undef BSTAGE

    float bz[4];
#pragma unroll
    for (int j = 0; j < 4; j++)
        bz[j] = bias[n0 + wc * 64 + j * 16 + lr];
#pragma unroll
    for (int i = 0; i < 4; i++)
#pragma unroll
        for (int r = 0; r < 4; r++) {
            int row = m0 + wr * 64 + i * 16 + quad * 4 + r;
#pragma unroll
            for (int j = 0; j < 4; j++)
                out[(size_t)row * EE + n0 + wc * 64 + j * 16 + lr] =
                    acc[i][j][r] + bz[j];
        }
}

// ---------------------------------------------------------------------------
extern "C" void kernel_launch(void* const* d_in, const int* in_sizes, int n_in,
                              void* d_out, int out_size, void* d_ws, size_t ws_size,
                              hipStream_t stream)
{
    (void)in_sizes; (void)n_in; (void)out_size;
    const float* x   = (const float*)d_in[0];
    const float* Wq  = (const float*)d_in[1];
    const float* Wk  = (const float*)d_in[2];
    const float* Wv  = (const float*)d_in[3];
    const float* Wu  = (const float*)d_in[4];
    const float* bu  = (const float*)d_in[5];
    const float* qg  = (const float*)d_in[6];
    const float* qbt = (const float*)d_in[7];
    const float* kg  = (const float*)d_in[8];
    const float* kbt = (const float*)d_in[9];
    float* out = (float*)d_out;

    bf16* Qb  = (bf16*)d_ws;                    // 16MB (doubles as attn-out)
    bf16* Kb  = Qb  + (size_t)8192 * 1024;
    bf16* Vb  = Kb  + (size_t)8192 * 1024;
    bf16* Wqb = Vb  + (size_t)8192 * 1024;      // 2MB each
    bf16* Wkb = Wqb + (size_t)1024 * 1024;
    bf16* Wvb = Wkb + (size_t)1024 * 1024;
    bf16* Wub = Wvb + (size_t)1024 * 1024;
    bf16* xb  = Wub + (size_t)1024 * 1024;      // 16MB

    const size_t need = ((size_t)3 * 8192 * 1024 + 4 * 1024 * 1024 + 8192 * 1024) * 2;
    const bool fast = ws_size >= need;

    cvt_all<<<dim3(512, 1, fast ? 12 : 4), 256, 0, stream>>>(
        Wq, Wk, Wv, Wu, x, Wqb, Wkb, Wvb, Wub, xb);
    if (fast)
        gemm_qkv_t<0><<<dim3(8, 64, 3), 256, 0, stream>>>(
            x, xb, Wqb, Wkb, Wvb, Qb, Kb, Vb, qg, qbt, kg, kbt);
    else
        gemm_qkv_t<1><<<dim3(8, 64, 3), 256, 0, stream>>>(
            x, nullptr, Wqb, Wkb, Wvb, Qb, Kb, Vb, qg, qbt, kg, kbt);
    flash<<<dim3(8, 64), 512, 0, stream>>>(Qb, Kb, Vb, Qb);
    gemm_bias<<<dim3(8, 64), 256, 0, stream>>>(Qb, Wub, bu, out);
}

// Round 9
// 260.250 us; speedup vs baseline: 1.1609x; 1.0350x over previous
//
#include <hip/hip_runtime.h>
#include <hip/hip_bf16.h>
#include <stdint.h>
#include <stddef.h>

// SelfAttention: B=4 T=2048 E=1024 H=16 S=64, causal, q/k LayerNorm over S.
// f32 in/out; bf16 MFMA compute.
//   0) cvt_all: Wq/Wk/Wv/Wu and x f32 -> bf16 (one pass).
//   1) gemm_qkv: Q/K/V = x@W^T, fused head-LayerNorm (q,k), SCALE*log2(e)
//      folded in Q.  XCD remap + 2-phase dbuf staging, counted vmcnt [r3],
//      XOR chunk swizzle [r7], compiler-scheduled inner loop [r8].
//      ROUND 9: __launch_bounds__(256,3) — r8 analysis: 104 VGPR + 64 AGPR
//      = 168 unified regs -> 176 @ 16-granularity -> only 2 waves/SIMD
//      (occupancy 20%).  Bound forces <=170 -> 3 waves/SIMD = 3 blocks/CU.
//   2) flash: r7 structure unchanged.
//   3) gemm_bias: ROUND 9: retiled 128x128 -> 64x128 (grid was 512 blocks
//      = exactly 2 blocks/CU SUPPLY — the r0-flash bug).  Now grid (8,128)
//      = 1024 uniform blocks = 4 blocks/CU, __launch_bounds__(256,4)
//      (acc[4][2] = 32 AGPR, fits easily).  Per-wave 64x32 out, 3 async16
//      per wave/kt, vmcnt(3), same XOR swizzle.  XCD owns 16 contiguous
//      m-tiles (A-set 2MB + Wu 2MB = L2-fit).
// Workspace: Q(=AO),K,V (48MB) + W bf16 (8MB) + xb (16MB) = 72MB (fallback
// template if ws_size < 72MB keeps the old f32-A staging, 1-phase loop).

using bf16 = __hip_bfloat16;
typedef __attribute__((ext_vector_type(8))) short s16x8;
typedef __attribute__((ext_vector_type(4))) short s16x4;
typedef __attribute__((ext_vector_type(4))) float f32x4;

#define MFMA16(a, b, c) __builtin_amdgcn_mfma_f32_16x16x32_bf16((a), (b), (c), 0, 0, 0)

static __device__ __forceinline__ s16x8 ld8(const bf16* p) {
    return *reinterpret_cast<const s16x8*>(p);
}
static __device__ __forceinline__ s16x8 ld8s(const short* p) {
    return *reinterpret_cast<const s16x8*>(p);
}
static __device__ __forceinline__ s16x8 cvt8(const float* p) {
    f32x4 u = *reinterpret_cast<const f32x4*>(p);
    f32x4 v = *reinterpret_cast<const f32x4*>(p + 4);
    s16x8 r;
#pragma unroll
    for (int e = 0; e < 4; e++) {
        r[e]     = __builtin_bit_cast(short, __float2bfloat16(u[e]));
        r[e + 4] = __builtin_bit_cast(short, __float2bfloat16(v[e]));
    }
    return r;
}
// packed f32x2 -> bf16x2 (RNE), 1 instr; no builtin on gfx950 (T12 recipe)
static __device__ __forceinline__ unsigned int cvtpk(float lo, float hi) {
    unsigned int r;
    asm("v_cvt_pk_bf16_f32 %0, %1, %2" : "=v"(r) : "v"(lo), "v"(hi));
    return r;
}

// async global(bf16)->LDS, 16B per lane; lds base must be wave-uniform.
static __device__ __forceinline__ void async16(short* lds, const bf16* g) {
    __builtin_amdgcn_global_load_lds(
        (const __attribute__((address_space(1))) unsigned int*)g,
        (__attribute__((address_space(3))) unsigned int*)lds, 16, 0, 0);
}

#define EE 1024

// ---------------------------------------------------------------------------
// f32 -> bf16: z=0..3 weights (1M each), z=4..11 x slices (8 x 1M)
// ---------------------------------------------------------------------------
__global__ __launch_bounds__(256) void cvt_all(
    const float* __restrict__ w0, const float* __restrict__ w1,
    const float* __restrict__ w2, const float* __restrict__ w3,
    const float* __restrict__ x,
    bf16* __restrict__ o0, bf16* __restrict__ o1,
    bf16* __restrict__ o2, bf16* __restrict__ o3, bf16* __restrict__ xb)
{
    const int z = blockIdx.z;
    const float* s;
    bf16* d;
    if (z < 4) {
        s = (z == 0) ? w0 : (z == 1) ? w1 : (z == 2) ? w2 : w3;
        d = (z == 0) ? o0 : (z == 1) ? o1 : (z == 2) ? o2 : o3;
    } else {
        s = x  + (size_t)(z - 4) * 1048576;
        d = xb + (size_t)(z - 4) * 1048576;
    }
    size_t i = ((size_t)blockIdx.x * 256 + threadIdx.x) * 8;
    *reinterpret_cast<s16x8*>(d + i) = cvt8(s + i);
}

// ---------------------------------------------------------------------------
// Fused QKV GEMM + head LayerNorm.  z=0:Q(+LN,*0.125*log2e) z=1:K(+LN) z=2:V
// AF32=0: 2-phase dbuf staging via global_load_lds from xb + XCD remap +
//         both-sides XOR chunk swizzle; launch_bounds(256,3) -> 3 blocks/CU.
// AF32=1: f32 cvt fallback (old 1-phase structure, linear LDS, no bound).
// ---------------------------------------------------------------------------
template <int AF32>
__global__ __launch_bounds__(256, AF32 ? 1 : 3) void gemm_qkv_t(
    const float* __restrict__ xf, const bf16* __restrict__ xb,
    const bf16* __restrict__ Wq, const bf16* __restrict__ Wk, const bf16* __restrict__ Wv,
    bf16* __restrict__ Qb, bf16* __restrict__ Kb, bf16* __restrict__ Vb,
    const float* __restrict__ qg, const float* __restrict__ qbt,
    const float* __restrict__ kg, const float* __restrict__ kbt)
{
    const int z = blockIdx.z;
    const bf16* Bt = (z == 0) ? Wq : (z == 1) ? Wk : Wv;
    bf16* out      = (z == 0) ? Qb : (z == 1) ? Kb : Vb;
    const float* gamma = (z == 0) ? qg : kg;
    const float* beta  = (z == 0) ? qbt : kbt;
    const bool  ln     = (z < 2);
    // log2(e) folded into Q so flash softmax is a bare exp2
    const float oscale = (z == 0) ? 0.125f * 1.44269504088896340736f : 1.0f;

    constexpr int LASZ = AF32 ? 128 * 40 : 2 * 4096;
    __shared__ __align__(16) short lA[LASZ];
    __shared__ __align__(16) short lB[2 * 4096];

    const int tid  = threadIdx.x;
    const int lane = tid & 63;
    const int w    = tid >> 6;
    const int wr = w >> 1, wc = w & 1;
    const int lr = lane & 15, quad = lane >> 4;

    // XCD-aware remap: XCD = flat%8 = blockIdx.x owns 8 contiguous m-panels
    const int mi = blockIdx.x * 8 + (blockIdx.y & 7);
    const int ni = blockIdx.y >> 3;
    const int m0 = mi * 128;
    const int n0 = ni * 128;

    const int strow = w * 32 + (lane >> 2);
    // both-sides XOR: source chunk = (lane&3)^(strow&3); read chunk = quad^(lr&3)
    const int stcol = AF32 ? (lane & 3) * 8
                           : (((lane & 3) ^ (strow & 3)) << 3);
    const bf16* bgl = Bt + (size_t)(n0 + strow) * EE + stcol;

    f32x4 acc[4][4];
#pragma unroll
    for (int i = 0; i < 4; i++)
#pragma unroll
        for (int j = 0; j < 4; j++) acc[i][j] = (f32x4){0.f, 0.f, 0.f, 0.f};

    if constexpr (AF32) {
        constexpr int SA = 40;
        const int sr  = tid >> 1;
        const int sc0 = (tid & 1) << 4;
        const float* ap = xf + (size_t)(m0 + sr) * EE + sc0;
        short* lap = lA + sr * SA + sc0;
        short* bl = lB + (w * 2) * 512;
        const short* lArd = lA + (wr * 64 + lr) * SA + quad * 8;
        const short* lBrd = lB + (wc * 64 + lr) * 32 + quad * 8;
        const bf16* bg = bgl;

        for (int kt = 0; kt < EE / 32; ++kt) {
            s16x8 a0 = cvt8(ap), a1 = cvt8(ap + 8);
            __syncthreads();
            *reinterpret_cast<s16x8*>(lap)     = a0;
            *reinterpret_cast<s16x8*>(lap + 8) = a1;
            async16(bl, bg);
            async16(bl + 512, bg + 16 * EE);
            ap += 32;
            bg += 32;
            __syncthreads();

            s16x8 af[4], bfr[4];
#pragma unroll
            for (int i = 0; i < 4; i++) af[i]  = ld8s(lArd + i * 16 * SA);
#pragma unroll
            for (int j = 0; j < 4; j++) bfr[j] = ld8s(lBrd + j * 16 * 32);
#pragma unroll
            for (int i = 0; i < 4; i++)
#pragma unroll
                for (int j = 0; j < 4; j++) acc[i][j] = MFMA16(af[i], bfr[j], acc[i][j]);
        }
    } else {
        const bf16* agl = xb + (size_t)(m0 + strow) * EE + stcol;
        short* const al0 = lA + w * 1024;
        short* const bl0 = lB + w * 1024;

#define QSTAGE(c, kt)                                                     \
    {                                                                     \
        short* al = al0 + (c) * 4096;                                     \
        short* bl = bl0 + (c) * 4096;                                     \
        const bf16* ag = agl + (kt) * 32;                                 \
        const bf16* bg = bgl + (kt) * 32;                                 \
        async16(al, ag); async16(al + 512, ag + 16 * EE);                 \
        async16(bl, bg); async16(bl + 512, bg + 16 * EE);                 \
    }

        QSTAGE(0, 0)
        // read chunk = quad ^ (row&3); row = w?*64 + lr -> row&3 = lr&3
        const int ard = (wr * 64 + lr) * 32 + ((quad ^ (lr & 3)) << 3);
        const int brd = (wc * 64 + lr) * 32 + ((quad ^ (lr & 3)) << 3);
#pragma unroll 1
        for (int kt = 0; kt < EE / 32; ++kt) {
            const int c = kt & 1;
            if (kt < EE / 32 - 1) {
                QSTAGE(c ^ 1, kt + 1)
                asm volatile("s_waitcnt vmcnt(4)" ::: "memory");
            } else {
                asm volatile("s_waitcnt vmcnt(0)" ::: "memory");
            }
            __builtin_amdgcn_s_barrier();   // stage(kt) landed for all waves

            // compiler-scheduled ds_read/MFMA interleave (r8)
            const short* lArd = lA + c * 4096 + ard;
            const short* lBrd = lB + c * 4096 + brd;
            s16x8 af[4], bfr[4];
#pragma unroll
            for (int i = 0; i < 4; i++) af[i]  = ld8s(lArd + i * 512);
#pragma unroll
            for (int j = 0; j < 4; j++) bfr[j] = ld8s(lBrd + j * 512);
#pragma unroll
            for (int i = 0; i < 4; i++)
#pragma unroll
                for (int j = 0; j < 4; j++) acc[i][j] = MFMA16(af[i], bfr[j], acc[i][j]);
            __builtin_amdgcn_s_barrier();   // reads of buf c done -> reusable
        }
#undef QSTAGE
    }

    if (ln) {
        float g[4], bt[4];
#pragma unroll
        for (int j = 0; j < 4; j++) {
            g[j]  = gamma[j * 16 + lr];
            bt[j] = beta[j * 16 + lr];
        }
#pragma unroll
        for (int i = 0; i < 4; i++) {
#pragma unroll
            for (int r = 0; r < 4; r++) {
                float s1 = 0.f, s2 = 0.f;
#pragma unroll
                for (int j = 0; j < 4; j++) {
                    float v = acc[i][j][r];
                    s1 += v;
                    s2 += v * v;
                }
#pragma unroll
                for (int off = 1; off < 16; off <<= 1) {
                    s1 += __shfl_xor(s1, off);
                    s2 += __shfl_xor(s2, off);
                }
                float mu  = s1 * (1.f / 64.f);
                float var = s2 * (1.f / 64.f) - mu * mu;
                float rs  = rsqrtf(var + 1e-5f);
                int row = m0 + wr * 64 + i * 16 + quad * 4 + r;
#pragma unroll
                for (int j = 0; j < 4; j++) {
                    float v = ((acc[i][j][r] - mu) * rs * g[j] + bt[j]) * oscale;
                    out[(size_t)row * EE + n0 + wc * 64 + j * 16 + lr] = __float2bfloat16(v);
                }
            }
        }
    } else {
#pragma unroll
        for (int i = 0; i < 4; i++)
#pragma unroll
            for (int r = 0; r < 4; r++) {
                int row = m0 + wr * 64 + i * 16 + quad * 4 + r;
#pragma unroll
                for (int j = 0; j < 4; j++)
                    out[(size_t)row * EE + n0 + wc * 64 + j * 16 + lr] =
                        __float2bfloat16(acc[i][j][r]);
            }
    }
}

// ---------------------------------------------------------------------------
// Causal flash attention.  grid (8,64), 512 thr = 8 waves x 16 q-rows,
// balanced pairs (pr, 15-pr) = equal 36-tile blocks, 2 blocks/CU.
// K tile: LDS dbuf via global_load_lds + both-sides XOR swizzle.
// VT/PT: XOR-swizzled 64-wide (chunk ^= row&7 on write AND read).
// V: reg prefetch + LDS transpose.  Counted waits; bare exp2f softmax;
// cvtpk; mask-split; setprio.  [unchanged from r7]
// ---------------------------------------------------------------------------
__global__ __launch_bounds__(512, 4) void flash(
    const bf16* __restrict__ Qb, const bf16* __restrict__ Kb,
    const bf16* __restrict__ Vb, bf16* __restrict__ Ob)
{
    const int flat = blockIdx.y * 8 + blockIdx.x;
    const int vid  = (flat & 7) * 64 + (flat >> 3);   // bijective XCD swizzle
    const int pr = vid & 7;
    const int bh = vid >> 3;
    const int b = bh >> 4, h = bh & 15;
    const int tid = threadIdx.x, lane = tid & 63, w = tid >> 6;   // w = 0..7
    const int lr = lane & 15, quad = lane >> 4;
    const size_t base = (size_t)b * 2048 * 1024 + h * 64;

    __shared__ __align__(16) short VT[64 * 64];     // V^T tile, XOR-swizzled
    __shared__ __align__(16) short PT[128 * 64];    // P tile, XOR-swizzled
    __shared__ __align__(16) short KS[2][64 * 64];  // K tiles, swizzled linear

    short* const prow = PT + (w * 16 + lr) * 64;    // wave-local P row base
    const int lr7 = lr & 7;
    const bf16* const kst = Kb + base + (size_t)(w * 8 + (lane >> 3)) * 1024 +
                            (((lane & 7) ^ (lane >> 3)) << 3);
    short* const kdst = &KS[0][0] + w * 512;
    const int kaddr0 = lr * 64 + ((quad ^ lr7) << 3);

#pragma unroll 1
    for (int ph = 0; ph < 2; ++ph) {
        const int qt = ph ? (15 - pr) : pr;
        const int tw = qt * 128 + w * 16;

        // Q fragments (B operand: col=query=lr, k=quad*8), resident all tiles
        s16x8 qf[2];
#pragma unroll
        for (int ks = 0; ks < 2; ks++)
            qf[ks] = ld8(Qb + base + (size_t)(tw + lr) * 1024 + ks * 32 + quad * 8);

        f32x4 o[4];
#pragma unroll
        for (int j = 0; j < 4; j++) o[j] = (f32x4){0.f, 0.f, 0.f, 0.f};
        float lsum = 0.f;

        const int nkt = 2 * qt + 2;   // even

        __syncthreads();   // KS/VT/PT reuse across phases (prev reads done)
        // prefetch tile 0: V to regs, K to KS[0]
        s16x8 va0 = ld8(Vb + base + (size_t)lane * 1024 + w * 8);
        s16x8 vb0;
        async16(kdst, kst);

#define FTILE(KT, V0C, KCUR, V0N, KNXT)                                          \
    {                                                                            \
        const int kb = (KT) * 64;                                                \
        const bool active = (kb <= tw + 15);                                     \
        asm volatile("s_waitcnt vmcnt(0)" ::: "memory"); /* K/V(t) landed */     \
        __builtin_amdgcn_s_barrier();  /* + prior iter's VT/PT reads done */     \
        _Pragma("unroll")                                                        \
        for (int e = 0; e < 8; e++)    /* V^T write, swizzled: row=w*8+e */      \
            VT[(w * 8 + e) * 64 + (((lane >> 3) ^ e) << 3) + (lane & 7)]         \
                = V0C[e];                                                        \
        const int kb2 = kb + 64;                                                 \
        if (kb2 < nkt * 64) { /* prefetch t+1; stays in flight across PV */      \
            async16(kdst + (KNXT) * 4096, kst + (size_t)kb2 * 1024);             \
            V0N = ld8(Vb + base + (size_t)(kb2 + lane) * 1024 + w * 8);          \
        }                                                                        \
        if (active) {                                                            \
            const short* kc = &KS[KCUR][0];                                      \
            f32x4 sc[4];                                                         \
            _Pragma("unroll")                                                    \
            for (int jk = 0; jk < 4; jk++) sc[jk] = (f32x4){0.f, 0.f, 0.f, 0.f}; \
            __builtin_amdgcn_s_setprio(1);                                       \
            _Pragma("unroll")                                                    \
            for (int ks = 0; ks < 2; ks++)                                       \
                _Pragma("unroll")                                                \
                for (int jk = 0; jk < 4; jk++) {                                 \
                    s16x8 kf = ld8s(kc + jk * 1024 + (kaddr0 ^ (ks * 32)));      \
                    sc[jk] = MFMA16(kf, qf[ks], sc[jk]);                         \
                }                                                                \
            __builtin_amdgcn_s_setprio(0);                                       \
            if (kb + 63 > tw) {          /* diagonal tile: causal mask */        \
                const int qq = tw + lr;                                          \
                _Pragma("unroll")                                                \
                for (int jk = 0; jk < 4; jk++) {                                 \
                    const int k0 = kb + jk * 16 + quad * 4;                      \
                    float p0 = exp2f(sc[jk][0]);                                 \
                    float p1 = exp2f(sc[jk][1]);                                 \
                    float p2 = exp2f(sc[jk][2]);                                 \
                    float p3 = exp2f(sc[jk][3]);                                 \
                    if (k0 + 0 > qq) p0 = 0.f;                                   \
                    if (k0 + 1 > qq) p1 = 0.f;                                   \
                    if (k0 + 2 > qq) p2 = 0.f;                                   \
                    if (k0 + 3 > qq) p3 = 0.f;                                   \
                    lsum += (p0 + p1) + (p2 + p3);                               \
                    uint2 pk = {cvtpk(p0, p1), cvtpk(p2, p3)};                   \
                    *reinterpret_cast<uint2*>(                                   \
                        prow + (((jk * 2 + (quad >> 1)) ^ lr7) << 3) +           \
                        ((quad & 1) << 2)) = pk;                                 \
                }                                                                \
            } else {                     /* interior tile: no mask */            \
                _Pragma("unroll")                                                \
                for (int jk = 0; jk < 4; jk++) {                                 \
                    float p0 = exp2f(sc[jk][0]);                                 \
                    float p1 = exp2f(sc[jk][1]);                                 \
                    float p2 = exp2f(sc[jk][2]);                                 \
                    float p3 = exp2f(sc[jk][3]);                                 \
                    lsum += (p0 + p1) + (p2 + p3);                               \
                    uint2 pk = {cvtpk(p0, p1), cvtpk(p2, p3)};                   \
                    *reinterpret_cast<uint2*>(                                   \
                        prow + (((jk * 2 + (quad >> 1)) ^ lr7) << 3) +           \
                        ((quad & 1) << 2)) = pk;                                 \
                }                                                                \
            }                                                                    \
        }                                                                        \
        asm volatile("s_waitcnt lgkmcnt(0)" ::: "memory"); /* VT/PT visible */   \
        __builtin_amdgcn_s_barrier();  /* prefetch NOT drained */                \
        if (active) {                                                            \
            _Pragma("unroll")                                                    \
            for (int ks = 0; ks < 2; ks++) {                                     \
                s16x8 pf = ld8s(prow + (((ks * 4 + quad) ^ lr7) << 3));          \
                s16x8 vf[4];                                                     \
                _Pragma("unroll")                                                \
                for (int j = 0; j < 4; j++)                                      \
                    vf[j] = ld8s(VT + (j * 16 + lr) * 64 +                       \
                                 (((ks * 4 + quad) ^ lr7) << 3));                \
                __builtin_amdgcn_s_setprio(1);                                   \
                _Pragma("unroll")                                                \
                for (int j = 0; j < 4; j++)                                      \
                    o[j] = MFMA16(pf, vf[j], o[j]);                              \
                __builtin_amdgcn_s_setprio(0);                                   \
            }                                                                    \
        }                                                                        \
    }

#pragma unroll 1
        for (int kt = 0; kt < nkt; kt += 2) {
            FTILE(kt,     va0, 0, vb0, 1)
            FTILE(kt + 1, vb0, 1, va0, 0)
        }
#undef FTILE

        // epilogue: finish l reduction (deferred), normalize, store
        float l = lsum;
        l += __shfl_xor(l, 16);
        l += __shfl_xor(l, 32);
#pragma unroll
        for (int r = 0; r < 4; r++) {
            float inv = 1.f / __shfl(l, quad * 4 + r);
            int t = tw + quad * 4 + r;
#pragma unroll
            for (int j = 0; j < 4; j++)
                Ob[base + (size_t)t * 1024 + j * 16 + lr] =
                    __float2bfloat16(o[j][r] * inv);
        }
    }
}

// ---------------------------------------------------------------------------
// out = A @ Wu^T + bu.  64x128 tiles, grid (8,128) = 1024 uniform blocks =
// 4 blocks/CU (was 512 = 2/CU supply cap).  4 waves, each 64x32 out
// (acc[4][2] = 32 AGPR).  2-phase dbuf, vmcnt(3), XOR swizzle, XCD remap
// (16 contiguous m-tiles per XCD: A-set 2MB + Wu 2MB = L2-fit).
// ---------------------------------------------------------------------------
__global__ __launch_bounds__(256, 4) void gemm_bias(
    const bf16* __restrict__ A, const bf16* __restrict__ Bt,
    const float* __restrict__ bias, float* __restrict__ out)
{
    __shared__ __align__(16) short lA[2 * 2048];   // 64 x 32 per buf
    __shared__ __align__(16) short lB[2 * 4096];   // 128 x 32 per buf

    const int tid  = threadIdx.x;
    const int lane = tid & 63;
    const int w    = tid >> 6;           // 0..3: n-column of 32
    const int lr = lane & 15, quad = lane >> 4;

    const int mi = blockIdx.x * 16 + (blockIdx.y & 15);   // 128 m-tiles
    const int ni = blockIdx.y >> 4;                       // 8 n-tiles
    const int m0 = mi * 64;
    const int n0 = ni * 128;

    // staging: A rows w*16+(lane>>2) (1 async16/wave); B rows w*32+(lane>>2)
    // and +16 (2 async16/wave).  Source chunk pre-XOR'd by row&3.
    const int srA = w * 16 + (lane >> 2);
    const int srB = w * 32 + (lane >> 2);
    const bf16* agl = A  + (size_t)(m0 + srA) * EE + (((lane & 3) ^ (srA & 3)) << 3);
    const bf16* bgl = Bt + (size_t)(n0 + srB) * EE + (((lane & 3) ^ (srB & 3)) << 3);
    short* const al0 = lA + w * 512;
    short* const bl0 = lB + w * 1024;

    f32x4 acc[4][2];
#pragma unroll
    for (int i = 0; i < 4; i++)
#pragma unroll
        for (int j = 0; j < 2; j++) acc[i][j] = (f32x4){0.f, 0.f, 0.f, 0.f};

#define BSTAGE(c, kt)                                                     \
    {                                                                     \
        const bf16* ag = agl + (kt) * 32;                                 \
        const bf16* bg = bgl + (kt) * 32;                                 \
        async16(al0 + (c) * 2048, ag);                                    \
        async16(bl0 + (c) * 4096, bg);                                    \
        async16(bl0 + (c) * 4096 + 512, bg + 16 * EE);                    \
    }

    BSTAGE(0, 0)
    // read chunk = quad ^ (row&3); row&3 = lr&3 for all fragment rows
    const int ard = lr * 32 + ((quad ^ (lr & 3)) << 3);
    const int brd = (w * 32 + lr) * 32 + ((quad ^ (lr & 3)) << 3);
#pragma unroll 1
    for (int kt = 0; kt < EE / 32; ++kt) {
        const int c = kt & 1;
        if (kt < EE / 32 - 1) {
            BSTAGE(c ^ 1, kt + 1)
            asm volatile("s_waitcnt vmcnt(3)" ::: "memory");
        } else {
            asm volatile("s_waitcnt vmcnt(0)" ::: "memory");
        }
        __builtin_amdgcn_s_barrier();

        const short* lArd = lA + c * 2048 + ard;
        const short* lBrd = lB + c * 4096 + brd;
        s16x8 af[4], bfr[2];
#pragma unroll
        for (int i = 0; i < 4; i++) af[i]  = ld8s(lArd + i * 512);
#pragma unroll
        for (int j = 0; j < 2; j++) bfr[j] = ld8s(lBrd + j * 512);
#pragma unroll
        for (int i = 0; i < 4; i++)
#pragma unroll
            for (int j = 0; j < 2; j++) acc[i][j] = MFMA16(af[i], bfr[j], acc[i][j]);
        __builtin_amdgcn_s_barrier();
    }
#undef BSTAGE

    float bz[2];
#pragma unroll
    for (int j = 0; j < 2; j++)
        bz[j] = bias[n0 + w * 32 + j * 16 + lr];
#pragma unroll
    for (int i = 0; i < 4; i++)
#pragma unroll
        for (int r = 0; r < 4; r++) {
            int row = m0 + i * 16 + quad * 4 + r;
#pragma unroll
            for (int j = 0; j < 2; j++)
                out[(size_t)row * EE + n0 + w * 32 + j * 16 + lr] =
                    acc[i][j][r] + bz[j];
        }
}

// ---------------------------------------------------------------------------
extern "C" void kernel_launch(void* const* d_in, const int* in_sizes, int n_in,
                              void* d_out, int out_size, void* d_ws, size_t ws_size,
                              hipStream_t stream)
{
    (void)in_sizes; (void)n_in; (void)out_size;
    const float* x   = (const float*)d_in[0];
    const float* Wq  = (const float*)d_in[1];
    const float* Wk  = (const float*)d_in[2];
    const float* Wv  = (const float*)d_in[3];
    const float* Wu  = (const float*)d_in[4];
    const float* bu  = (const float*)d_in[5];
    const float* qg  = (const float*)d_in[6];
    const float* qbt = (const float*)d_in[7];
    const float* kg  = (const float*)d_in[8];
    const float* kbt = (const float*)d_in[9];
    float* out = (float*)d_out;

    bf16* Qb  = (bf16*)d_ws;                    // 16MB (doubles as attn-out)
    bf16* Kb  = Qb  + (size_t)8192 * 1024;
    bf16* Vb  = Kb  + (size_t)8192 * 1024;
    bf16* Wqb = Vb  + (size_t)8192 * 1024;      // 2MB each
    bf16* Wkb = Wqb + (size_t)1024 * 1024;
    bf16* Wvb = Wkb + (size_t)1024 * 1024;
    bf16* Wub = Wvb + (size_t)1024 * 1024;
    bf16* xb  = Wub + (size_t)1024 * 1024;      // 16MB

    const size_t need = ((size_t)3 * 8192 * 1024 + 4 * 1024 * 1024 + 8192 * 1024) * 2;
    const bool fast = ws_size >= need;

    cvt_all<<<dim3(512, 1, fast ? 12 : 4), 256, 0, stream>>>(
        Wq, Wk, Wv, Wu, x, Wqb, Wkb, Wvb, Wub, xb);
    if (fast)
        gemm_qkv_t<0><<<dim3(8, 64, 3), 256, 0, stream>>>(
            x, xb, Wqb, Wkb, Wvb, Qb, Kb, Vb, qg, qbt, kg, kbt);
    else
        gemm_qkv_t<1><<<dim3(8, 64, 3), 256, 0, stream>>>(
            x, nullptr, Wqb, Wkb, Wvb, Qb, Kb, Vb, qg, qbt, kg, kbt);
    flash<<<dim3(8, 64), 512, 0, stream>>>(Qb, Kb, Vb, Qb);
    gemm_bias<<<dim3(8, 128), 256, 0, stream>>>(Qb, Wub, bu, out);
}